// Round 4
// baseline (243.369 us; speedup 1.0000x reference)
//
#include <hip/hip_runtime.h>

typedef short bhalf8 __attribute__((ext_vector_type(8)));   // 8 x bf16 = 4 VGPRs
typedef float floatx4 __attribute__((ext_vector_type(4)));  // MFMA C/D frag

#define D_MODEL 1024
#define SEQ     2048
#define BATCH   2
#define NHEAD   16
#define DH      64

// global -> LDS direct DMA (m97: width 16 emits global_load_lds_dwordx4).
// LDS dest is WAVE-UNIFORM base; lane i lands at base + i*16 (no padding!).
#define GLDS(g, l) __builtin_amdgcn_global_load_lds( \
    (const __attribute__((address_space(1))) void*)(g), \
    (__attribute__((address_space(3))) void*)(l), 16, 0, 0)

static __device__ __forceinline__ short f2bf(float f) {
    unsigned u = __builtin_bit_cast(unsigned, f);
    u = (u + 0x7fffu + ((u >> 16) & 1u)) >> 16;   // RNE fp32 -> bf16
    return (short)u;
}
static __device__ __forceinline__ unsigned pack2(float a, float b) {
    return (unsigned)(unsigned short)f2bf(a) | ((unsigned)(unsigned short)f2bf(b) << 16);
}
// HW packed fp32->bf16 (RNE); no builtin on gfx950, inline asm per T12 recipe.
static __device__ __forceinline__ unsigned cvt_pk_bf16(float lo, float hi) {
    unsigned r;
    asm("v_cvt_pk_bf16_f32 %0, %1, %2" : "=v"(r) : "v"(lo), "v"(hi));
    return r;
}

// ---------------------------------------------------------------------------
// Casts: fp32 -> bf16. cast_w packs wq,wk,wv,wo into one [4096][1024] region.
// ---------------------------------------------------------------------------
__global__ __launch_bounds__(256) void cast_x(const float* __restrict__ s,
                                              short* __restrict__ d) {
    int i = (blockIdx.x * 256 + threadIdx.x) * 8;
    float4 a = *(const float4*)(s + i);
    float4 b = *(const float4*)(s + i + 4);
    uint4 u = {pack2(a.x, a.y), pack2(a.z, a.w), pack2(b.x, b.y), pack2(b.z, b.w)};
    *(uint4*)(d + i) = u;
}

__global__ __launch_bounds__(256) void cast_w(const float* __restrict__ wq,
                                              const float* __restrict__ wk,
                                              const float* __restrict__ wv,
                                              const float* __restrict__ wo,
                                              short* __restrict__ dst) {
    const float* s = (blockIdx.y == 0) ? wq : (blockIdx.y == 1) ? wk
                   : (blockIdx.y == 2) ? wv : wo;
    size_t off = (size_t)blockIdx.y * (D_MODEL * D_MODEL);
    int i = (blockIdx.x * 256 + threadIdx.x) * 8;
    float4 a = *(const float4*)(s + i);
    float4 b = *(const float4*)(s + i + 4);
    uint4 u = {pack2(a.x, a.y), pack2(a.z, a.w), pack2(b.x, b.y), pack2(b.z, b.w)};
    *(uint4*)(dst + off + i) = u;
}

// ---------------------------------------------------------------------------
// Fused QKV GEMM, m97-style staging: M=4096, K=1024, N=3072.
// by<8 -> Qo[m][n], by<16 -> Ko[m][n], else Vt[n][m] (transpose via LDS).
// ---------------------------------------------------------------------------
__global__ __launch_bounds__(256) void gemm_qkv(const short* __restrict__ A,
                                                const short* __restrict__ W,
                                                short* __restrict__ Qo,
                                                short* __restrict__ Ko,
                                                short* __restrict__ Vt) {
    __shared__ __align__(16) char pool[34816];
    short (*As)[64] = (short(*)[64])pool;             // 128x64 = 16384 B
    short (*Bs)[64] = (short(*)[64])(pool + 16384);   // 128x64 = 16384 B
    const int t    = threadIdx.x;
    const int wave = t >> 6, lane = t & 63, quad = lane >> 4, l16 = lane & 15;
    const int bm = blockIdx.x * 128, by = blockIdx.y, bn = by * 128;
    const int qm = (wave >> 1) * 64, qn = (wave & 1) * 64;

    const int lrow = lane >> 3, lcol = (lane & 7) * 8;
    const short* Ag = A + (size_t)(bm + wave * 32 + lrow) * 1024 + lcol;
    const short* Wg = W + (size_t)(bn + wave * 32 + lrow) * 1024 + lcol;
    short* Al = &As[wave * 32][0];     // wave-uniform LDS bases
    short* Bl = &Bs[wave * 32][0];

    floatx4 acc[4][4];
#pragma unroll
    for (int i = 0; i < 4; ++i)
#pragma unroll
        for (int j = 0; j < 4; ++j) {
            floatx4 z = {0.f, 0.f, 0.f, 0.f};
            acc[i][j] = z;
        }

    for (int k0 = 0; k0 < 1024; k0 += 64) {
        __syncthreads();
#pragma unroll
        for (int j = 0; j < 4; ++j) {
            GLDS(Ag + k0 + (size_t)j * 8 * 1024, Al + j * 8 * 64);
            GLDS(Wg + k0 + (size_t)j * 8 * 1024, Bl + j * 8 * 64);
        }
        __syncthreads();
#pragma unroll
        for (int kk = 0; kk < 64; kk += 32) {
            bhalf8 af[4], bfr[4];
#pragma unroll
            for (int im = 0; im < 4; ++im)
                af[im] = *(const bhalf8*)&As[qm + im * 16 + l16][kk + quad * 8];
#pragma unroll
            for (int jn = 0; jn < 4; ++jn)
                bfr[jn] = *(const bhalf8*)&Bs[qn + jn * 16 + l16][kk + quad * 8];
#pragma unroll
            for (int im = 0; im < 4; ++im)
#pragma unroll
                for (int jn = 0; jn < 4; ++jn)
                    acc[im][jn] = __builtin_amdgcn_mfma_f32_16x16x32_bf16(
                        af[im], bfr[jn], acc[im][jn], 0, 0, 0);
        }
    }

    // ---- epilogue: stage C tile in LDS, line-complete wide stores ----
    __syncthreads();
    short (*Ct)[136] = (short(*)[136])pool;           // 128x136x2 = 34816 B
    const bool isV = (by >= 16);
#pragma unroll
    for (int im = 0; im < 4; ++im)
#pragma unroll
        for (int jn = 0; jn < 4; ++jn)
#pragma unroll
            for (int g = 0; g < 4; ++g) {
                const int ml = qm + im * 16 + quad * 4 + g;
                const int nl = qn + jn * 16 + l16;
                if (isV) Ct[nl][ml] = f2bf(acc[im][jn][g]);   // transposed [n][m]
                else     Ct[ml][nl] = f2bf(acc[im][jn][g]);
            }
    __syncthreads();

    short* outp;
    size_t rowbase, colbase, stride;
    if (by < 8)       { outp = Qo; rowbase = bm;                colbase = bn;        stride = 1024; }
    else if (by < 16) { outp = Ko; rowbase = bm;                colbase = bn - 1024; stride = 1024; }
    else              { outp = Vt; rowbase = (size_t)bn - 2048; colbase = bm;        stride = 4096; }
#pragma unroll
    for (int pass = 0; pass < 8; ++pass) {
        const int r = (t >> 4) + pass * 16;
        const int c = (t & 15) * 8;
        uint4 u = *(const uint4*)&Ct[r][c];
        *(uint4*)(outp + (rowbase + r) * stride + colbase + c) = u;
    }
}

// ---------------------------------------------------------------------------
// O-projection GEMM, m97-style: A = Y [4096][1024] bf16, W = wob, C fp32.
// ---------------------------------------------------------------------------
__global__ __launch_bounds__(256) void gemm_o(const short* __restrict__ A,
                                              const short* __restrict__ W,
                                              float* __restrict__ C) {
    __shared__ __align__(16) char pool[34816];
    short (*As)[64] = (short(*)[64])pool;             // 128x64 = 16384 B
    short (*Bs)[64] = (short(*)[64])(pool + 16384);   //  64x64 =  8192 B
    const int t    = threadIdx.x;
    const int wave = t >> 6, lane = t & 63, quad = lane >> 4, l16 = lane & 15;
    const int bm = blockIdx.x * 128, bn = blockIdx.y * 64;
    const int qm = (wave >> 1) * 64, qn = (wave & 1) * 32;

    const int lrow = lane >> 3, lcol = (lane & 7) * 8;
    const short* Ag = A + (size_t)(bm + wave * 32 + lrow) * 1024 + lcol;
    const short* Wg = W + (size_t)(bn + wave * 16 + lrow) * 1024 + lcol;
    short* Al = &As[wave * 32][0];
    short* Bl = &Bs[wave * 16][0];

    floatx4 acc[4][2];
#pragma unroll
    for (int i = 0; i < 4; ++i)
#pragma unroll
        for (int j = 0; j < 2; ++j) {
            floatx4 z = {0.f, 0.f, 0.f, 0.f};
            acc[i][j] = z;
        }

    for (int k0 = 0; k0 < 1024; k0 += 64) {
        __syncthreads();
#pragma unroll
        for (int j = 0; j < 4; ++j)
            GLDS(Ag + k0 + (size_t)j * 8 * 1024, Al + j * 8 * 64);
#pragma unroll
        for (int j = 0; j < 2; ++j)
            GLDS(Wg + k0 + (size_t)j * 8 * 1024, Bl + j * 8 * 64);
        __syncthreads();
#pragma unroll
        for (int kk = 0; kk < 64; kk += 32) {
            bhalf8 af[4], bfr[2];
#pragma unroll
            for (int im = 0; im < 4; ++im)
                af[im] = *(const bhalf8*)&As[qm + im * 16 + l16][kk + quad * 8];
#pragma unroll
            for (int jn = 0; jn < 2; ++jn)
                bfr[jn] = *(const bhalf8*)&Bs[qn + jn * 16 + l16][kk + quad * 8];
#pragma unroll
            for (int im = 0; im < 4; ++im)
#pragma unroll
                for (int jn = 0; jn < 2; ++jn)
                    acc[im][jn] = __builtin_amdgcn_mfma_f32_16x16x32_bf16(
                        af[im], bfr[jn], acc[im][jn], 0, 0, 0);
        }
    }

    // ---- fp32 LDS epilogue, line-complete stores ----
    __syncthreads();
    float (*Ctf)[68] = (float(*)[68])pool;            // 128x68x4 = 34816 B
#pragma unroll
    for (int im = 0; im < 4; ++im)
#pragma unroll
        for (int jn = 0; jn < 2; ++jn)
#pragma unroll
            for (int g = 0; g < 4; ++g)
                Ctf[qm + im * 16 + quad * 4 + g][qn + jn * 16 + l16] = acc[im][jn][g];
    __syncthreads();
#pragma unroll
    for (int pass = 0; pass < 8; ++pass) {
        const int r = (t >> 4) + pass * 16;
        const int c = (t & 15) * 4;
        float4 u = *(const float4*)&Ctf[r][c];
        *(float4*)(C + (size_t)(bm + r) * 1024 + bn + c) = u;
    }
}

// ---------------------------------------------------------------------------
// Flash attention v11 — v10's 4-wave balanced split + head->XCD locality.
// v10 post-mortem: spills fixed, 4 blocks/CU resident, but FETCH_SIZE blew
// up 12.4 -> 71 MB and VALUBusy stayed 34%: grid (j,bh) round-robins one
// head's 32 blocks across all 8 XCDs, so each XCD's 128 resident blocks
// span all 32 heads = 16 MB K/V >> 4 MB L2 -> every K/V load at L3
// latency, serial chains lengthened, occupancy gain nullified.
// v11: 1D grid, bijective decode with xcd = wg&7 tied to bh (v7's
// accidental locality, now explicit): per XCD only 4 heads resident
// = 2 MB K/V, L2-fit. Plus s_setprio(1) around MFMA clusters (T5: +4-7%
// on independent-wave attn, m191).
// Schedule per block (one strip-pair: light j, heavy 63-j; 33 chunks):
//   wave 0: heavy prefix even chunks (9) | wave 1: heavy odd (8)
//   wave 2: light even -> park -> heavy-tail even (<=8)
//   wave 3: light odd  -> park -> heavy-tail odd  (<=7)
// Fixed-CB softmax => partials over disjoint k-sets are additive.
// ---------------------------------------------------------------------------
#define LOADQ(qf, qwv) do {                                                   \
    _Pragma("unroll")                                                         \
    for (int im_ = 0; im_ < 2; ++im_) {                                       \
        const short* qr_ = Qbase + (size_t)((qwv) + im_ * 16 + l16) * 1024;   \
        qf[im_][0] = *(const bhalf8*)(qr_ + quad * 8);                        \
        qf[im_][1] = *(const bhalf8*)(qr_ + 32 + quad * 8);                   \
    } } while (0)

#define LOADK(dst, kk) do {                                                   \
    _Pragma("unroll")                                                         \
    for (int jn_ = 0; jn_ < 4; ++jn_) {                                       \
        const short* kr_ = Kbase + (size_t)((kk) + jn_ * 16 + l16) * 1024 + quad * 8; \
        dst[jn_][0] = *(const bhalf8*)(kr_);                                  \
        dst[jn_][1] = *(const bhalf8*)(kr_ + 32);                             \
    } } while (0)

#define LOADV(dst, kk) do {                                                   \
    _Pragma("unroll")                                                         \
    for (int nd_ = 0; nd_ < 4; ++nd_) {                                       \
        const short* vr_ = Vbase + (size_t)(nd_ * 16 + l16) * 4096 + (kk) + quad * 8; \
        dst[nd_][0] = *(const bhalf8*)(vr_);                                  \
        dst[nd_][1] = *(const bhalf8*)(vr_ + 32);                             \
    } } while (0)

#define ZERO_ACC() do {                                                       \
    _Pragma("unroll")                                                         \
    for (int im_ = 0; im_ < 2; ++im_) {                                       \
        _Pragma("unroll")                                                     \
        for (int g_ = 0; g_ < 4; ++g_) lsum[im_][g_] = 0.f;                   \
        _Pragma("unroll")                                                     \
        for (int nd_ = 0; nd_ < 4; ++nd_) {                                   \
            floatx4 z_ = {0.f, 0.f, 0.f, 0.f};                                \
            o[im_][nd_] = z_;                                                 \
        }                                                                     \
    } } while (0)

// One 64-k chunk: S = Q K^T, prefetch next K, softmax -> Ps, O += P V,
// prefetch next V. kf/vt are rotating single buffers.
#define CHUNK(k0v, knv, qf, qwv) do {                                         \
    floatx4 s_[2][4];                                                         \
    __builtin_amdgcn_s_setprio(1);                                            \
    _Pragma("unroll")                                                         \
    for (int im_ = 0; im_ < 2; ++im_)                                         \
        _Pragma("unroll")                                                     \
        for (int jn_ = 0; jn_ < 4; ++jn_) {                                   \
            floatx4 z_ = {0.f, 0.f, 0.f, 0.f};                                \
            z_ = __builtin_amdgcn_mfma_f32_16x16x32_bf16(qf[im_][0], kf[jn_][0], z_, 0, 0, 0); \
            z_ = __builtin_amdgcn_mfma_f32_16x16x32_bf16(qf[im_][1], kf[jn_][1], z_, 0, 0, 0); \
            s_[im_][jn_] = z_;                                                \
        }                                                                     \
    __builtin_amdgcn_s_setprio(0);                                            \
    LOADK(kf, knv);                        /* kf dead after S-MFMAs */        \
    const bool partial_ = ((k0v) + 64 > (qwv));                               \
    _Pragma("unroll")                                                         \
    for (int im_ = 0; im_ < 2; ++im_)                                         \
        _Pragma("unroll")                                                     \
        for (int g_ = 0; g_ < 4; ++g_) {                                      \
            const int rr_ = im_ * 16 + quad * 4 + g_;                         \
            const int qrow_ = (qwv) + rr_;                                    \
            float e0_ = exp2f(s_[im_][0][g_] * KS - CB);                      \
            float e1_ = exp2f(s_[im_][1][g_] * KS - CB);                      \
            float e2_ = exp2f(s_[im_][2][g_] * KS - CB);                      \
            float e3_ = exp2f(s_[im_][3][g_] * KS - CB);                      \
            if (partial_) {                                                   \
                if ((k0v) + l16 > qrow_)      e0_ = 0.f;                      \
                if ((k0v) + 16 + l16 > qrow_) e1_ = 0.f;                      \
                if ((k0v) + 32 + l16 > qrow_) e2_ = 0.f;                      \
                if ((k0v) + 48 + l16 > qrow_) e3_ = 0.f;                      \
            }                                                                 \
            lsum[im_][g_] += (e0_ + e1_) + (e2_ + e3_);                       \
            unsigned r01_ = cvt_pk_bf16(e0_, e1_);                            \
            unsigned r23_ = cvt_pk_bf16(e2_, e3_);                            \
            Ps[wave][rr_][l16]      = (short)r01_;                            \
            Ps[wave][rr_][16 + l16] = (short)(r01_ >> 16);                    \
            Ps[wave][rr_][32 + l16] = (short)r23_;                            \
            Ps[wave][rr_][48 + l16] = (short)(r23_ >> 16);                    \
        }                                                                     \
    _Pragma("unroll")                                                         \
    for (int im_ = 0; im_ < 2; ++im_) {                                       \
        bhalf8 ap0_ = *(const bhalf8*)&Ps[wave][im_ * 16 + l16][quad * 8];    \
        bhalf8 ap1_ = *(const bhalf8*)&Ps[wave][im_ * 16 + l16][32 + quad * 8]; \
        __builtin_amdgcn_s_setprio(1);                                        \
        _Pragma("unroll")                                                     \
        for (int nd_ = 0; nd_ < 4; ++nd_) {                                   \
            o[im_][nd_] = __builtin_amdgcn_mfma_f32_16x16x32_bf16(ap0_, vt[nd_][0], o[im_][nd_], 0, 0, 0); \
            o[im_][nd_] = __builtin_amdgcn_mfma_f32_16x16x32_bf16(ap1_, vt[nd_][1], o[im_][nd_], 0, 0, 0); \
        }                                                                     \
        __builtin_amdgcn_s_setprio(0);                                        \
    }                                                                         \
    LOADV(vt, knv);                        /* vt dead after PV */             \
} while (0)

// Chunk segment k0 = base + step*i, i in [0,n), rotating prefetch.
#define RUN_SEG(nseg, kbase, kstep, qf, qwv) do {                             \
    const int n_ = (nseg);                                                    \
    const int base_ = (kbase);                                                \
    if (n_ > 0) {                                                             \
        LOADK(kf, base_);                                                     \
        LOADV(vt, base_);                                                     \
        _Pragma("unroll 1")                                                   \
        for (int i_ = 0; i_ < n_; ++i_) {                                     \
            const int k0_ = base_ + i_ * (kstep);                             \
            const int kn_ = (i_ + 1 < n_) ? (k0_ + (kstep)) : base_;          \
            CHUNK(k0_, kn_, qf, qwv);                                         \
        }                                                                     \
    } } while (0)

#define REDUCE_LSUM() do {                                                    \
    _Pragma("unroll")                                                         \
    for (int im_ = 0; im_ < 2; ++im_)                                         \
        _Pragma("unroll")                                                     \
        for (int g_ = 0; g_ < 4; ++g_) {                                      \
            float r_ = lsum[im_][g_];                                         \
            r_ += __shfl_xor(r_, 1, 64);                                      \
            r_ += __shfl_xor(r_, 2, 64);                                      \
            r_ += __shfl_xor(r_, 4, 64);                                      \
            r_ += __shfl_xor(r_, 8, 64);                                      \
            lsum[im_][g_] = r_;                                               \
        } } while (0)

// Partial (o, lsum) <-> LDS slot: float[64][40] per slot, lane-private row.
#define WRITE_PART(slot_) do {                                                \
    float* cp_ = (float*)(slot_) + lane * 40;                                 \
    _Pragma("unroll")                                                         \
    for (int im_ = 0; im_ < 2; ++im_)                                         \
        _Pragma("unroll")                                                     \
        for (int nd_ = 0; nd_ < 4; ++nd_)                                     \
            *(floatx4*)(cp_ + (im_ * 4 + nd_) * 4) = o[im_][nd_];             \
    _Pragma("unroll")                                                         \
    for (int im_ = 0; im_ < 2; ++im_)                                         \
        _Pragma("unroll")                                                     \
        for (int g_ = 0; g_ < 4; ++g_)                                        \
            cp_[32 + im_ * 4 + g_] = lsum[im_][g_];                           \
    } while (0)

#define ACCUM_PART(slot_) do {                                                \
    const float* cp_ = (const float*)(slot_) + lane * 40;                     \
    _Pragma("unroll")                                                         \
    for (int im_ = 0; im_ < 2; ++im_)                                         \
        _Pragma("unroll")                                                     \
        for (int nd_ = 0; nd_ < 4; ++nd_)                                     \
            o[im_][nd_] += *(const floatx4*)(cp_ + (im_ * 4 + nd_) * 4);      \
    _Pragma("unroll")                                                         \
    for (int im_ = 0; im_ < 2; ++im_)                                         \
        _Pragma("unroll")                                                     \
        for (int g_ = 0; g_ < 4; ++g_)                                        \
            lsum[im_][g_] += cp_[32 + im_ * 4 + g_];                          \
    } while (0)

#define STORE_OUT(qwv) do {                                                   \
    _Pragma("unroll")                                                         \
    for (int im_ = 0; im_ < 2; ++im_)                                         \
        _Pragma("unroll")                                                     \
        for (int g_ = 0; g_ < 4; ++g_) {                                      \
            const float iv_ = 1.0f / lsum[im_][g_];                           \
            const int qrow_ = (qwv) + im_ * 16 + quad * 4 + g_;               \
            _Pragma("unroll")                                                 \
            for (int nd_ = 0; nd_ < 4; ++nd_)                                 \
                Y[(size_t)(b * SEQ + qrow_) * 1024 + h * 64 + nd_ * 16 + l16] = \
                    f2bf(o[im_][nd_][g_] * iv_);                              \
        } } while (0)

__global__ __launch_bounds__(256) void attn_v11(const short* __restrict__ Qo,
                                                const short* __restrict__ Ko,
                                                const short* __restrict__ Vt,
                                                short* __restrict__ Y) {
    // Layout: Ps [4][32][72] bf16 = 18432 B (per-wave P staging);
    // PsR (heavy-odd partial of wave 1) ALIASES Ps (used only after bar1);
    // Cmb[2] = float[2][64][40] = 20480 B (non-aliased: written mid-compute).
    __shared__ __align__(16) char pool[38912];
    short (*Ps)[32][72] = (short(*)[32][72])pool;
    float* PsR  = (float*)pool;                        // [64][40] = 10240 B
    float* Cmb0 = (float*)(pool + 18432);              // [64][40]
    float* Cmb1 = (float*)(pool + 18432 + 10240);      // [64][40]

    const int t    = threadIdx.x;
    const int wave = t >> 6, lane = t & 63, quad = lane >> 4, l16 = lane & 15;
    // Bijective decode tying head to XCD: wg & 7 = dispatch XCD (round-robin).
    // Per XCD: heads {xcd, xcd+8, xcd+16, xcd+24} only -> 2 MB K/V, L2-fit.
    const int wg  = (int)blockIdx.x;
    const int xcd = wg & 7;
    const int w2  = wg >> 3;                           // 0..127
    const int bh  = xcd + ((w2 >> 5) << 3);            // 0..31
    const int j   = w2 & 31;                           // strip-pair id, 0..31
    const int b = bh >> 4, h = bh & 15;
    const int qwH = (63 - j) * 32, qwL = j * 32;
    const int ncL  = (j + 2) >> 1;                     // light chunks, 1..16
    const int tail = ((65 - j) >> 1) - 17;             // heavy tail chunks, 0..15

    const short* Qbase = Qo + (size_t)b * SEQ * 1024 + h * 64;
    const short* Kbase = Ko + (size_t)b * SEQ * 1024 + h * 64;
    const short* Vbase = Vt + (size_t)h * 64 * 4096 + (size_t)b * SEQ;

    const float KS = 0.125f * 1.44269504f;   // score scale * log2(e)
    const float CB = 12.0f * 1.44269504f;    // fixed softmax offset

    bhalf8 kf[4][2], vt[4][2], qf[2][2];     // rotating prefetch buffers
    float lsum[2][4];
    floatx4 o[2][4];
    ZERO_ACC();

    const bool isB = (wave >= 2);
    const int  par = wave & 1;
    // Segment 1: waves 0/1 -> heavy prefix parity halves; waves 2/3 ->
    // light strip parity halves.
    {
        const int qw1 = isB ? qwL : qwH;
        const int n1  = isB ? (par ? (ncL >> 1) : ((ncL + 1) >> 1))
                            : (par ? 8 : 9);
        LOADQ(qf, qw1);
        RUN_SEG(n1, par * 64, 128, qf, qw1);
        REDUCE_LSUM();
    }
    // Segment 2 (B-waves only): park light partial, then heavy-tail parity.
    if (isB) {
        WRITE_PART(par ? Cmb1 : Cmb0);
        ZERO_ACC();
        const int n2 = par ? (tail >> 1) : ((tail + 1) >> 1);
        LOADQ(qf, qwH);
        RUN_SEG(n2, 1088 + par * 64, 128, qf, qwH);
        REDUCE_LSUM();
    }

    __syncthreads();                       // bar1: all Ps dead, Cmb light final
    if (wave == 1) WRITE_PART(PsR);        // heavy-odd partial into dead Ps
    __syncthreads();                       // bar2
    if (wave == 0) {
        ACCUM_PART(PsR);                   // heavy: even + odd prefix
    } else if (wave == 1) {                // wave 1 regs now free: light final
        ZERO_ACC();
        ACCUM_PART(Cmb0);
        ACCUM_PART(Cmb1);
        STORE_OUT(qwL);
    }
    __syncthreads();                       // bar3: Cmb free for heavy reuse
    if (wave == 2)      WRITE_PART(Cmb0);  // heavy-tail even partial
    else if (wave == 3) WRITE_PART(Cmb1);  // heavy-tail odd partial
    __syncthreads();                       // bar4
    if (wave == 0) {
        ACCUM_PART(Cmb0);
        ACCUM_PART(Cmb1);
        STORE_OUT(qwH);
    }
}

// ---------------------------------------------------------------------------
extern "C" void kernel_launch(void* const* d_in, const int* in_sizes, int n_in,
                              void* d_out, int out_size, void* d_ws, size_t ws_size,
                              hipStream_t stream) {
    const float* x  = (const float*)d_in[0];
    const float* wq = (const float*)d_in[1];
    const float* wk = (const float*)d_in[2];
    const float* wv = (const float*)d_in[3];
    const float* wo = (const float*)d_in[4];

    short* xb   = (short*)d_ws;
    short* Qo   = xb + (size_t)4096 * 1024;
    short* Ko   = Qo + (size_t)4096 * 1024;
    short* Vt   = Ko + (size_t)4096 * 1024;
    short* wall = Vt + (size_t)1024 * 4096;
    short* wob  = wall + (size_t)3 * 1024 * 1024;

    cast_x<<<dim3(2048), 256, 0, stream>>>(x, xb);
    cast_w<<<dim3(512, 4), 256, 0, stream>>>(wq, wk, wv, wo, wall);
    gemm_qkv<<<dim3(32, 24), 256, 0, stream>>>(xb, wall, Qo, Ko, Vt);
    attn_v11<<<dim3(1024), 256, 0, stream>>>(Qo, Ko, Vt, xb);
    gemm_o<<<dim3(32, 16), 256, 0, stream>>>(xb, wob, (float*)d_out);
}

// Round 5
// 230.188 us; speedup vs baseline: 1.0573x; 1.0573x over previous
//
#include <hip/hip_runtime.h>

typedef short bhalf8 __attribute__((ext_vector_type(8)));   // 8 x bf16 = 4 VGPRs
typedef float floatx4 __attribute__((ext_vector_type(4)));  // MFMA C/D frag

#define D_MODEL 1024
#define SEQ     2048
#define BATCH   2
#define NHEAD   16
#define DH      64

// global -> LDS direct DMA (m97: width 16 emits global_load_lds_dwordx4).
// LDS dest is WAVE-UNIFORM base; lane i lands at base + i*16 (no padding!).
#define GLDS(g, l) __builtin_amdgcn_global_load_lds( \
    (const __attribute__((address_space(1))) void*)(g), \
    (__attribute__((address_space(3))) void*)(l), 16, 0, 0)

static __device__ __forceinline__ short f2bf(float f) {
    unsigned u = __builtin_bit_cast(unsigned, f);
    u = (u + 0x7fffu + ((u >> 16) & 1u)) >> 16;   // RNE fp32 -> bf16
    return (short)u;
}
static __device__ __forceinline__ unsigned pack2(float a, float b) {
    return (unsigned)(unsigned short)f2bf(a) | ((unsigned)(unsigned short)f2bf(b) << 16);
}
// HW packed fp32->bf16 (RNE); no builtin on gfx950, inline asm per T12 recipe.
static __device__ __forceinline__ unsigned cvt_pk_bf16(float lo, float hi) {
    unsigned r;
    asm("v_cvt_pk_bf16_f32 %0, %1, %2" : "=v"(r) : "v"(lo), "v"(hi));
    return r;
}

// ---------------------------------------------------------------------------
// Casts: fp32 -> bf16. cast_w packs wq,wk,wv,wo into one [4096][1024] region.
// ---------------------------------------------------------------------------
__global__ __launch_bounds__(256) void cast_x(const float* __restrict__ s,
                                              short* __restrict__ d) {
    int i = (blockIdx.x * 256 + threadIdx.x) * 8;
    float4 a = *(const float4*)(s + i);
    float4 b = *(const float4*)(s + i + 4);
    uint4 u = {pack2(a.x, a.y), pack2(a.z, a.w), pack2(b.x, b.y), pack2(b.z, b.w)};
    *(uint4*)(d + i) = u;
}

__global__ __launch_bounds__(256) void cast_w(const float* __restrict__ wq,
                                              const float* __restrict__ wk,
                                              const float* __restrict__ wv,
                                              const float* __restrict__ wo,
                                              short* __restrict__ dst) {
    const float* s = (blockIdx.y == 0) ? wq : (blockIdx.y == 1) ? wk
                   : (blockIdx.y == 2) ? wv : wo;
    size_t off = (size_t)blockIdx.y * (D_MODEL * D_MODEL);
    int i = (blockIdx.x * 256 + threadIdx.x) * 8;
    float4 a = *(const float4*)(s + i);
    float4 b = *(const float4*)(s + i + 4);
    uint4 u = {pack2(a.x, a.y), pack2(a.z, a.w), pack2(b.x, b.y), pack2(b.z, b.w)};
    *(uint4*)(dst + off + i) = u;
}

// ---------------------------------------------------------------------------
// Fused QKV GEMM, m97-style staging: M=4096, K=1024, N=3072.
// by<8 -> Qo[m][n], by<16 -> Ko[m][n], else Vt[n][m] (transpose via LDS).
// ---------------------------------------------------------------------------
__global__ __launch_bounds__(256) void gemm_qkv(const short* __restrict__ A,
                                                const short* __restrict__ W,
                                                short* __restrict__ Qo,
                                                short* __restrict__ Ko,
                                                short* __restrict__ Vt) {
    __shared__ __align__(16) char pool[34816];
    short (*As)[64] = (short(*)[64])pool;             // 128x64 = 16384 B
    short (*Bs)[64] = (short(*)[64])(pool + 16384);   // 128x64 = 16384 B
    const int t    = threadIdx.x;
    const int wave = t >> 6, lane = t & 63, quad = lane >> 4, l16 = lane & 15;
    const int bm = blockIdx.x * 128, by = blockIdx.y, bn = by * 128;
    const int qm = (wave >> 1) * 64, qn = (wave & 1) * 64;

    const int lrow = lane >> 3, lcol = (lane & 7) * 8;
    const short* Ag = A + (size_t)(bm + wave * 32 + lrow) * 1024 + lcol;
    const short* Wg = W + (size_t)(bn + wave * 32 + lrow) * 1024 + lcol;
    short* Al = &As[wave * 32][0];     // wave-uniform LDS bases
    short* Bl = &Bs[wave * 32][0];

    floatx4 acc[4][4];
#pragma unroll
    for (int i = 0; i < 4; ++i)
#pragma unroll
        for (int j = 0; j < 4; ++j) {
            floatx4 z = {0.f, 0.f, 0.f, 0.f};
            acc[i][j] = z;
        }

    for (int k0 = 0; k0 < 1024; k0 += 64) {
        __syncthreads();
#pragma unroll
        for (int j = 0; j < 4; ++j) {
            GLDS(Ag + k0 + (size_t)j * 8 * 1024, Al + j * 8 * 64);
            GLDS(Wg + k0 + (size_t)j * 8 * 1024, Bl + j * 8 * 64);
        }
        __syncthreads();
#pragma unroll
        for (int kk = 0; kk < 64; kk += 32) {
            bhalf8 af[4], bfr[4];
#pragma unroll
            for (int im = 0; im < 4; ++im)
                af[im] = *(const bhalf8*)&As[qm + im * 16 + l16][kk + quad * 8];
#pragma unroll
            for (int jn = 0; jn < 4; ++jn)
                bfr[jn] = *(const bhalf8*)&Bs[qn + jn * 16 + l16][kk + quad * 8];
#pragma unroll
            for (int im = 0; im < 4; ++im)
#pragma unroll
                for (int jn = 0; jn < 4; ++jn)
                    acc[im][jn] = __builtin_amdgcn_mfma_f32_16x16x32_bf16(
                        af[im], bfr[jn], acc[im][jn], 0, 0, 0);
        }
    }

    // ---- epilogue: stage C tile in LDS, line-complete wide stores ----
    __syncthreads();
    short (*Ct)[136] = (short(*)[136])pool;           // 128x136x2 = 34816 B
    const bool isV = (by >= 16);
#pragma unroll
    for (int im = 0; im < 4; ++im)
#pragma unroll
        for (int jn = 0; jn < 4; ++jn)
#pragma unroll
            for (int g = 0; g < 4; ++g) {
                const int ml = qm + im * 16 + quad * 4 + g;
                const int nl = qn + jn * 16 + l16;
                if (isV) Ct[nl][ml] = f2bf(acc[im][jn][g]);   // transposed [n][m]
                else     Ct[ml][nl] = f2bf(acc[im][jn][g]);
            }
    __syncthreads();

    short* outp;
    size_t rowbase, colbase, stride;
    if (by < 8)       { outp = Qo; rowbase = bm;                colbase = bn;        stride = 1024; }
    else if (by < 16) { outp = Ko; rowbase = bm;                colbase = bn - 1024; stride = 1024; }
    else              { outp = Vt; rowbase = (size_t)bn - 2048; colbase = bm;        stride = 4096; }
#pragma unroll
    for (int pass = 0; pass < 8; ++pass) {
        const int r = (t >> 4) + pass * 16;
        const int c = (t & 15) * 8;
        uint4 u = *(const uint4*)&Ct[r][c];
        *(uint4*)(outp + (rowbase + r) * stride + colbase + c) = u;
    }
}

// ---------------------------------------------------------------------------
// O-projection GEMM, m97-style: A = Y [4096][1024] bf16, W = wob, C fp32.
// ---------------------------------------------------------------------------
__global__ __launch_bounds__(256) void gemm_o(const short* __restrict__ A,
                                              const short* __restrict__ W,
                                              float* __restrict__ C) {
    __shared__ __align__(16) char pool[34816];
    short (*As)[64] = (short(*)[64])pool;             // 128x64 = 16384 B
    short (*Bs)[64] = (short(*)[64])(pool + 16384);   //  64x64 =  8192 B
    const int t    = threadIdx.x;
    const int wave = t >> 6, lane = t & 63, quad = lane >> 4, l16 = lane & 15;
    const int bm = blockIdx.x * 128, bn = blockIdx.y * 64;
    const int qm = (wave >> 1) * 64, qn = (wave & 1) * 32;

    const int lrow = lane >> 3, lcol = (lane & 7) * 8;
    const short* Ag = A + (size_t)(bm + wave * 32 + lrow) * 1024 + lcol;
    const short* Wg = W + (size_t)(bn + wave * 16 + lrow) * 1024 + lcol;
    short* Al = &As[wave * 32][0];
    short* Bl = &Bs[wave * 16][0];

    floatx4 acc[4][2];
#pragma unroll
    for (int i = 0; i < 4; ++i)
#pragma unroll
        for (int j = 0; j < 2; ++j) {
            floatx4 z = {0.f, 0.f, 0.f, 0.f};
            acc[i][j] = z;
        }

    for (int k0 = 0; k0 < 1024; k0 += 64) {
        __syncthreads();
#pragma unroll
        for (int j = 0; j < 4; ++j)
            GLDS(Ag + k0 + (size_t)j * 8 * 1024, Al + j * 8 * 64);
#pragma unroll
        for (int j = 0; j < 2; ++j)
            GLDS(Wg + k0 + (size_t)j * 8 * 1024, Bl + j * 8 * 64);
        __syncthreads();
#pragma unroll
        for (int kk = 0; kk < 64; kk += 32) {
            bhalf8 af[4], bfr[2];
#pragma unroll
            for (int im = 0; im < 4; ++im)
                af[im] = *(const bhalf8*)&As[qm + im * 16 + l16][kk + quad * 8];
#pragma unroll
            for (int jn = 0; jn < 2; ++jn)
                bfr[jn] = *(const bhalf8*)&Bs[qn + jn * 16 + l16][kk + quad * 8];
#pragma unroll
            for (int im = 0; im < 4; ++im)
#pragma unroll
                for (int jn = 0; jn < 2; ++jn)
                    acc[im][jn] = __builtin_amdgcn_mfma_f32_16x16x32_bf16(
                        af[im], bfr[jn], acc[im][jn], 0, 0, 0);
        }
    }

    // ---- fp32 LDS epilogue, line-complete stores ----
    __syncthreads();
    float (*Ctf)[68] = (float(*)[68])pool;            // 128x68x4 = 34816 B
#pragma unroll
    for (int im = 0; im < 4; ++im)
#pragma unroll
        for (int jn = 0; jn < 2; ++jn)
#pragma unroll
            for (int g = 0; g < 4; ++g)
                Ctf[qm + im * 16 + quad * 4 + g][qn + jn * 16 + l16] = acc[im][jn][g];
    __syncthreads();
#pragma unroll
    for (int pass = 0; pass < 8; ++pass) {
        const int r = (t >> 4) + pass * 16;
        const int c = (t & 15) * 4;
        float4 u = *(const float4*)&Ctf[r][c];
        *(float4*)(C + (size_t)(bm + r) * 1024 + bn + c) = u;
    }
}

// ---------------------------------------------------------------------------
// Flash attention v12 — v10 schedule + v11 locality, NO setprio.
// v11 post-mortem: bijective head->XCD decode fixed FETCH (71 -> 12.4 MB,
// L2-fit confirmed) but setprio (a) pushed VGPR 120 -> 132, crossing the
// 128 boundary where waves/CU HALVES (m69: steps at 64/128/256) -> measured
// occupancy halved 19 -> 10.3%; (b) T5 needs phase role-split to pay
// (m190: ~0/negative without it). v12 removes all setprio, keeping the
// decode: the previously-untested clean cell {16 waves/CU, L2-fit, no
// spills, no fences}. Body is bit-identical to v10's (VGPR 120 there).
// Schedule per block (one strip-pair: light j, heavy 63-j; 33 chunks):
//   wave 0: heavy prefix even chunks (9) | wave 1: heavy odd (8)
//   wave 2: light even -> park -> heavy-tail even (<=8)
//   wave 3: light odd  -> park -> heavy-tail odd  (<=7)
// Fixed-CB softmax => partials over disjoint k-sets are additive.
// Falsifier (pre-committed): attn >= 72 us with FETCH ~12.4 MB and
// VGPR <= 128 => occupancy is exhausted; next round shortens the chunk
// serial chain (swapped-QK^T in-register softmax, no Ps round-trip).
// ---------------------------------------------------------------------------
#define LOADQ(qf, qwv) do {                                                   \
    _Pragma("unroll")                                                         \
    for (int im_ = 0; im_ < 2; ++im_) {                                       \
        const short* qr_ = Qbase + (size_t)((qwv) + im_ * 16 + l16) * 1024;   \
        qf[im_][0] = *(const bhalf8*)(qr_ + quad * 8);                        \
        qf[im_][1] = *(const bhalf8*)(qr_ + 32 + quad * 8);                   \
    } } while (0)

#define LOADK(dst, kk) do {                                                   \
    _Pragma("unroll")                                                         \
    for (int jn_ = 0; jn_ < 4; ++jn_) {                                       \
        const short* kr_ = Kbase + (size_t)((kk) + jn_ * 16 + l16) * 1024 + quad * 8; \
        dst[jn_][0] = *(const bhalf8*)(kr_);                                  \
        dst[jn_][1] = *(const bhalf8*)(kr_ + 32);                             \
    } } while (0)

#define LOADV(dst, kk) do {                                                   \
    _Pragma("unroll")                                                         \
    for (int nd_ = 0; nd_ < 4; ++nd_) {                                       \
        const short* vr_ = Vbase + (size_t)(nd_ * 16 + l16) * 4096 + (kk) + quad * 8; \
        dst[nd_][0] = *(const bhalf8*)(vr_);                                  \
        dst[nd_][1] = *(const bhalf8*)(vr_ + 32);                             \
    } } while (0)

#define ZERO_ACC() do {                                                       \
    _Pragma("unroll")                                                         \
    for (int im_ = 0; im_ < 2; ++im_) {                                       \
        _Pragma("unroll")                                                     \
        for (int g_ = 0; g_ < 4; ++g_) lsum[im_][g_] = 0.f;                   \
        _Pragma("unroll")                                                     \
        for (int nd_ = 0; nd_ < 4; ++nd_) {                                   \
            floatx4 z_ = {0.f, 0.f, 0.f, 0.f};                                \
            o[im_][nd_] = z_;                                                 \
        }                                                                     \
    } } while (0)

// One 64-k chunk: S = Q K^T, prefetch next K, softmax -> Ps, O += P V,
// prefetch next V. kf/vt are rotating single buffers.
#define CHUNK(k0v, knv, qf, qwv) do {                                         \
    floatx4 s_[2][4];                                                         \
    _Pragma("unroll")                                                         \
    for (int im_ = 0; im_ < 2; ++im_)                                         \
        _Pragma("unroll")                                                     \
        for (int jn_ = 0; jn_ < 4; ++jn_) {                                   \
            floatx4 z_ = {0.f, 0.f, 0.f, 0.f};                                \
            z_ = __builtin_amdgcn_mfma_f32_16x16x32_bf16(qf[im_][0], kf[jn_][0], z_, 0, 0, 0); \
            z_ = __builtin_amdgcn_mfma_f32_16x16x32_bf16(qf[im_][1], kf[jn_][1], z_, 0, 0, 0); \
            s_[im_][jn_] = z_;                                                \
        }                                                                     \
    LOADK(kf, knv);                        /* kf dead after S-MFMAs */        \
    const bool partial_ = ((k0v) + 64 > (qwv));                               \
    _Pragma("unroll")                                                         \
    for (int im_ = 0; im_ < 2; ++im_)                                         \
        _Pragma("unroll")                                                     \
        for (int g_ = 0; g_ < 4; ++g_) {                                      \
            const int rr_ = im_ * 16 + quad * 4 + g_;                         \
            const int qrow_ = (qwv) + rr_;                                    \
            float e0_ = exp2f(s_[im_][0][g_] * KS - CB);                      \
            float e1_ = exp2f(s_[im_][1][g_] * KS - CB);                      \
            float e2_ = exp2f(s_[im_][2][g_] * KS - CB);                      \
            float e3_ = exp2f(s_[im_][3][g_] * KS - CB);                      \
            if (partial_) {                                                   \
                if ((k0v) + l16 > qrow_)      e0_ = 0.f;                      \
                if ((k0v) + 16 + l16 > qrow_) e1_ = 0.f;                      \
                if ((k0v) + 32 + l16 > qrow_) e2_ = 0.f;                      \
                if ((k0v) + 48 + l16 > qrow_) e3_ = 0.f;                      \
            }                                                                 \
            lsum[im_][g_] += (e0_ + e1_) + (e2_ + e3_);                       \
            unsigned r01_ = cvt_pk_bf16(e0_, e1_);                            \
            unsigned r23_ = cvt_pk_bf16(e2_, e3_);                            \
            Ps[wave][rr_][l16]      = (short)r01_;                            \
            Ps[wave][rr_][16 + l16] = (short)(r01_ >> 16);                    \
            Ps[wave][rr_][32 + l16] = (short)r23_;                            \
            Ps[wave][rr_][48 + l16] = (short)(r23_ >> 16);                    \
        }                                                                     \
    _Pragma("unroll")                                                         \
    for (int im_ = 0; im_ < 2; ++im_) {                                       \
        bhalf8 ap0_ = *(const bhalf8*)&Ps[wave][im_ * 16 + l16][quad * 8];    \
        bhalf8 ap1_ = *(const bhalf8*)&Ps[wave][im_ * 16 + l16][32 + quad * 8]; \
        _Pragma("unroll")                                                     \
        for (int nd_ = 0; nd_ < 4; ++nd_) {                                   \
            o[im_][nd_] = __builtin_amdgcn_mfma_f32_16x16x32_bf16(ap0_, vt[nd_][0], o[im_][nd_], 0, 0, 0); \
            o[im_][nd_] = __builtin_amdgcn_mfma_f32_16x16x32_bf16(ap1_, vt[nd_][1], o[im_][nd_], 0, 0, 0); \
        }                                                                     \
    }                                                                         \
    LOADV(vt, knv);                        /* vt dead after PV */             \
} while (0)

// Chunk segment k0 = base + step*i, i in [0,n), rotating prefetch.
#define RUN_SEG(nseg, kbase, kstep, qf, qwv) do {                             \
    const int n_ = (nseg);                                                    \
    const int base_ = (kbase);                                                \
    if (n_ > 0) {                                                             \
        LOADK(kf, base_);                                                     \
        LOADV(vt, base_);                                                     \
        _Pragma("unroll 1")                                                   \
        for (int i_ = 0; i_ < n_; ++i_) {                                     \
            const int k0_ = base_ + i_ * (kstep);                             \
            const int kn_ = (i_ + 1 < n_) ? (k0_ + (kstep)) : base_;          \
            CHUNK(k0_, kn_, qf, qwv);                                         \
        }                                                                     \
    } } while (0)

#define REDUCE_LSUM() do {                                                    \
    _Pragma("unroll")                                                         \
    for (int im_ = 0; im_ < 2; ++im_)                                         \
        _Pragma("unroll")                                                     \
        for (int g_ = 0; g_ < 4; ++g_) {                                      \
            float r_ = lsum[im_][g_];                                         \
            r_ += __shfl_xor(r_, 1, 64);                                      \
            r_ += __shfl_xor(r_, 2, 64);                                      \
            r_ += __shfl_xor(r_, 4, 64);                                      \
            r_ += __shfl_xor(r_, 8, 64);                                      \
            lsum[im_][g_] = r_;                                               \
        } } while (0)

// Partial (o, lsum) <-> LDS slot: float[64][40] per slot, lane-private row.
#define WRITE_PART(slot_) do {                                                \
    float* cp_ = (float*)(slot_) + lane * 40;                                 \
    _Pragma("unroll")                                                         \
    for (int im_ = 0; im_ < 2; ++im_)                                         \
        _Pragma("unroll")                                                     \
        for (int nd_ = 0; nd_ < 4; ++nd_)                                     \
            *(floatx4*)(cp_ + (im_ * 4 + nd_) * 4) = o[im_][nd_];             \
    _Pragma("unroll")                                                         \
    for (int im_ = 0; im_ < 2; ++im_)                                         \
        _Pragma("unroll")                                                     \
        for (int g_ = 0; g_ < 4; ++g_)                                        \
            cp_[32 + im_ * 4 + g_] = lsum[im_][g_];                           \
    } while (0)

#define ACCUM_PART(slot_) do {                                                \
    const float* cp_ = (const float*)(slot_) + lane * 40;                     \
    _Pragma("unroll")                                                         \
    for (int im_ = 0; im_ < 2; ++im_)                                         \
        _Pragma("unroll")                                                     \
        for (int nd_ = 0; nd_ < 4; ++nd_)                                     \
            o[im_][nd_] += *(const floatx4*)(cp_ + (im_ * 4 + nd_) * 4);      \
    _Pragma("unroll")                                                         \
    for (int im_ = 0; im_ < 2; ++im_)                                         \
        _Pragma("unroll")                                                     \
        for (int g_ = 0; g_ < 4; ++g_)                                        \
            lsum[im_][g_] += cp_[32 + im_ * 4 + g_];                          \
    } while (0)

#define STORE_OUT(qwv) do {                                                   \
    _Pragma("unroll")                                                         \
    for (int im_ = 0; im_ < 2; ++im_)                                         \
        _Pragma("unroll")                                                     \
        for (int g_ = 0; g_ < 4; ++g_) {                                      \
            const float iv_ = 1.0f / lsum[im_][g_];                           \
            const int qrow_ = (qwv) + im_ * 16 + quad * 4 + g_;               \
            _Pragma("unroll")                                                 \
            for (int nd_ = 0; nd_ < 4; ++nd_)                                 \
                Y[(size_t)(b * SEQ + qrow_) * 1024 + h * 64 + nd_ * 16 + l16] = \
                    f2bf(o[im_][nd_][g_] * iv_);                              \
        } } while (0)

__global__ __launch_bounds__(256) void attn_v12(const short* __restrict__ Qo,
                                                const short* __restrict__ Ko,
                                                const short* __restrict__ Vt,
                                                short* __restrict__ Y) {
    // Layout: Ps [4][32][72] bf16 = 18432 B (per-wave P staging);
    // PsR (heavy-odd partial of wave 1) ALIASES Ps (used only after bar1);
    // Cmb[2] = float[2][64][40] = 20480 B (non-aliased: written mid-compute).
    __shared__ __align__(16) char pool[38912];
    short (*Ps)[32][72] = (short(*)[32][72])pool;
    float* PsR  = (float*)pool;                        // [64][40] = 10240 B
    float* Cmb0 = (float*)(pool + 18432);              // [64][40]
    float* Cmb1 = (float*)(pool + 18432 + 10240);      // [64][40]

    const int t    = threadIdx.x;
    const int wave = t >> 6, lane = t & 63, quad = lane >> 4, l16 = lane & 15;
    // Bijective decode tying head to XCD: wg & 7 = dispatch XCD (round-robin).
    // Per XCD: heads {xcd, xcd+8, xcd+16, xcd+24} only -> 2 MB K/V, L2-fit.
    const int wg  = (int)blockIdx.x;
    const int xcd = wg & 7;
    const int w2  = wg >> 3;                           // 0..127
    const int bh  = xcd + ((w2 >> 5) << 3);            // 0..31
    const int j   = w2 & 31;                           // strip-pair id, 0..31
    const int b = bh >> 4, h = bh & 15;
    const int qwH = (63 - j) * 32, qwL = j * 32;
    const int ncL  = (j + 2) >> 1;                     // light chunks, 1..16
    const int tail = ((65 - j) >> 1) - 17;             // heavy tail chunks, 0..15

    const short* Qbase = Qo + (size_t)b * SEQ * 1024 + h * 64;
    const short* Kbase = Ko + (size_t)b * SEQ * 1024 + h * 64;
    const short* Vbase = Vt + (size_t)h * 64 * 4096 + (size_t)b * SEQ;

    const float KS = 0.125f * 1.44269504f;   // score scale * log2(e)
    const float CB = 12.0f * 1.44269504f;    // fixed softmax offset

    bhalf8 kf[4][2], vt[4][2], qf[2][2];     // rotating prefetch buffers
    float lsum[2][4];
    floatx4 o[2][4];
    ZERO_ACC();

    const bool isB = (wave >= 2);
    const int  par = wave & 1;
    // Segment 1: waves 0/1 -> heavy prefix parity halves; waves 2/3 ->
    // light strip parity halves.
    {
        const int qw1 = isB ? qwL : qwH;
        const int n1  = isB ? (par ? (ncL >> 1) : ((ncL + 1) >> 1))
                            : (par ? 8 : 9);
        LOADQ(qf, qw1);
        RUN_SEG(n1, par * 64, 128, qf, qw1);
        REDUCE_LSUM();
    }
    // Segment 2 (B-waves only): park light partial, then heavy-tail parity.
    if (isB) {
        WRITE_PART(par ? Cmb1 : Cmb0);
        ZERO_ACC();
        const int n2 = par ? (tail >> 1) : ((tail + 1) >> 1);
        LOADQ(qf, qwH);
        RUN_SEG(n2, 1088 + par * 64, 128, qf, qwH);
        REDUCE_LSUM();
    }

    __syncthreads();                       // bar1: all Ps dead, Cmb light final
    if (wave == 1) WRITE_PART(PsR);        // heavy-odd partial into dead Ps
    __syncthreads();                       // bar2
    if (wave == 0) {
        ACCUM_PART(PsR);                   // heavy: even + odd prefix
    } else if (wave == 1) {                // wave 1 regs now free: light final
        ZERO_ACC();
        ACCUM_PART(Cmb0);
        ACCUM_PART(Cmb1);
        STORE_OUT(qwL);
    }
    __syncthreads();                       // bar3: Cmb free for heavy reuse
    if (wave == 2)      WRITE_PART(Cmb0);  // heavy-tail even partial
    else if (wave == 3) WRITE_PART(Cmb1);  // heavy-tail odd partial
    __syncthreads();                       // bar4
    if (wave == 0) {
        ACCUM_PART(Cmb0);
        ACCUM_PART(Cmb1);
        STORE_OUT(qwH);
    }
}

// ---------------------------------------------------------------------------
extern "C" void kernel_launch(void* const* d_in, const int* in_sizes, int n_in,
                              void* d_out, int out_size, void* d_ws, size_t ws_size,
                              hipStream_t stream) {
    const float* x  = (const float*)d_in[0];
    const float* wq = (const float*)d_in[1];
    const float* wk = (const float*)d_in[2];
    const float* wv = (const float*)d_in[3];
    const float* wo = (const float*)d_in[4];

    short* xb   = (short*)d_ws;
    short* Qo   = xb + (size_t)4096 * 1024;
    short* Ko   = Qo + (size_t)4096 * 1024;
    short* Vt   = Ko + (size_t)4096 * 1024;
    short* wall = Vt + (size_t)1024 * 4096;
    short* wob  = wall + (size_t)3 * 1024 * 1024;

    cast_x<<<dim3(2048), 256, 0, stream>>>(x, xb);
    cast_w<<<dim3(512, 4), 256, 0, stream>>>(wq, wk, wv, wo, wall);
    gemm_qkv<<<dim3(32, 24), 256, 0, stream>>>(xb, wall, Qo, Ko, Vt);
    attn_v12<<<dim3(1024), 256, 0, stream>>>(Qo, Ko, Vt, xb);
    gemm_o<<<dim3(32, 16), 256, 0, stream>>>(xb, wob, (float*)d_out);
}

// Round 6
// 204.200 us; speedup vs baseline: 1.1918x; 1.1273x over previous
//
#include <hip/hip_runtime.h>

typedef short bhalf8 __attribute__((ext_vector_type(8)));   // 8 x bf16 = 4 VGPRs
typedef float floatx4 __attribute__((ext_vector_type(4)));  // MFMA C/D frag

#define D_MODEL 1024
#define SEQ     2048
#define BATCH   2
#define NHEAD   16
#define DH      64

// global -> LDS direct DMA (m97: width 16 emits global_load_lds_dwordx4).
// LDS dest is WAVE-UNIFORM base; lane i lands at base + i*16 (no padding!).
#define GLDS(g, l) __builtin_amdgcn_global_load_lds( \
    (const __attribute__((address_space(1))) void*)(g), \
    (__attribute__((address_space(3))) void*)(l), 16, 0, 0)

static __device__ __forceinline__ short f2bf(float f) {
    unsigned u = __builtin_bit_cast(unsigned, f);
    u = (u + 0x7fffu + ((u >> 16) & 1u)) >> 16;   // RNE fp32 -> bf16
    return (short)u;
}
static __device__ __forceinline__ unsigned pack2(float a, float b) {
    return (unsigned)(unsigned short)f2bf(a) | ((unsigned)(unsigned short)f2bf(b) << 16);
}
// HW packed fp32->bf16 (RNE); no builtin on gfx950, inline asm per T12 recipe.
static __device__ __forceinline__ unsigned cvt_pk_bf16(float lo, float hi) {
    unsigned r;
    asm("v_cvt_pk_bf16_f32 %0, %1, %2" : "=v"(r) : "v"(lo), "v"(hi));
    return r;
}

// ---------------------------------------------------------------------------
// Casts: fp32 -> bf16. cast_w packs wq,wk,wv,wo into one [4096][1024] region.
// ---------------------------------------------------------------------------
__global__ __launch_bounds__(256) void cast_x(const float* __restrict__ s,
                                              short* __restrict__ d) {
    int i = (blockIdx.x * 256 + threadIdx.x) * 8;
    float4 a = *(const float4*)(s + i);
    float4 b = *(const float4*)(s + i + 4);
    uint4 u = {pack2(a.x, a.y), pack2(a.z, a.w), pack2(b.x, b.y), pack2(b.z, b.w)};
    *(uint4*)(d + i) = u;
}

__global__ __launch_bounds__(256) void cast_w(const float* __restrict__ wq,
                                              const float* __restrict__ wk,
                                              const float* __restrict__ wv,
                                              const float* __restrict__ wo,
                                              short* __restrict__ dst) {
    const float* s = (blockIdx.y == 0) ? wq : (blockIdx.y == 1) ? wk
                   : (blockIdx.y == 2) ? wv : wo;
    size_t off = (size_t)blockIdx.y * (D_MODEL * D_MODEL);
    int i = (blockIdx.x * 256 + threadIdx.x) * 8;
    float4 a = *(const float4*)(s + i);
    float4 b = *(const float4*)(s + i + 4);
    uint4 u = {pack2(a.x, a.y), pack2(a.z, a.w), pack2(b.x, b.y), pack2(b.z, b.w)};
    *(uint4*)(dst + off + i) = u;
}

// ---------------------------------------------------------------------------
// Fused QKV GEMM, m97-style staging: M=4096, K=1024, N=3072.
// by<8 -> Qo[m][n], by<16 -> Ko[m][n], else Vt[n][m] (transpose via LDS).
// ---------------------------------------------------------------------------
__global__ __launch_bounds__(256) void gemm_qkv(const short* __restrict__ A,
                                                const short* __restrict__ W,
                                                short* __restrict__ Qo,
                                                short* __restrict__ Ko,
                                                short* __restrict__ Vt) {
    __shared__ __align__(16) char pool[34816];
    short (*As)[64] = (short(*)[64])pool;             // 128x64 = 16384 B
    short (*Bs)[64] = (short(*)[64])(pool + 16384);   // 128x64 = 16384 B
    const int t    = threadIdx.x;
    const int wave = t >> 6, lane = t & 63, quad = lane >> 4, l16 = lane & 15;
    const int bm = blockIdx.x * 128, by = blockIdx.y, bn = by * 128;
    const int qm = (wave >> 1) * 64, qn = (wave & 1) * 64;

    const int lrow = lane >> 3, lcol = (lane & 7) * 8;
    const short* Ag = A + (size_t)(bm + wave * 32 + lrow) * 1024 + lcol;
    const short* Wg = W + (size_t)(bn + wave * 32 + lrow) * 1024 + lcol;
    short* Al = &As[wave * 32][0];     // wave-uniform LDS bases
    short* Bl = &Bs[wave * 32][0];

    floatx4 acc[4][4];
#pragma unroll
    for (int i = 0; i < 4; ++i)
#pragma unroll
        for (int j = 0; j < 4; ++j) {
            floatx4 z = {0.f, 0.f, 0.f, 0.f};
            acc[i][j] = z;
        }

    for (int k0 = 0; k0 < 1024; k0 += 64) {
        __syncthreads();
#pragma unroll
        for (int j = 0; j < 4; ++j) {
            GLDS(Ag + k0 + (size_t)j * 8 * 1024, Al + j * 8 * 64);
            GLDS(Wg + k0 + (size_t)j * 8 * 1024, Bl + j * 8 * 64);
        }
        __syncthreads();
#pragma unroll
        for (int kk = 0; kk < 64; kk += 32) {
            bhalf8 af[4], bfr[4];
#pragma unroll
            for (int im = 0; im < 4; ++im)
                af[im] = *(const bhalf8*)&As[qm + im * 16 + l16][kk + quad * 8];
#pragma unroll
            for (int jn = 0; jn < 4; ++jn)
                bfr[jn] = *(const bhalf8*)&Bs[qn + jn * 16 + l16][kk + quad * 8];
#pragma unroll
            for (int im = 0; im < 4; ++im)
#pragma unroll
                for (int jn = 0; jn < 4; ++jn)
                    acc[im][jn] = __builtin_amdgcn_mfma_f32_16x16x32_bf16(
                        af[im], bfr[jn], acc[im][jn], 0, 0, 0);
        }
    }

    // ---- epilogue: stage C tile in LDS, line-complete wide stores ----
    __syncthreads();
    short (*Ct)[136] = (short(*)[136])pool;           // 128x136x2 = 34816 B
    const bool isV = (by >= 16);
#pragma unroll
    for (int im = 0; im < 4; ++im)
#pragma unroll
        for (int jn = 0; jn < 4; ++jn)
#pragma unroll
            for (int g = 0; g < 4; ++g) {
                const int ml = qm + im * 16 + quad * 4 + g;
                const int nl = qn + jn * 16 + l16;
                if (isV) Ct[nl][ml] = f2bf(acc[im][jn][g]);   // transposed [n][m]
                else     Ct[ml][nl] = f2bf(acc[im][jn][g]);
            }
    __syncthreads();

    short* outp;
    size_t rowbase, colbase, stride;
    if (by < 8)       { outp = Qo; rowbase = bm;                colbase = bn;        stride = 1024; }
    else if (by < 16) { outp = Ko; rowbase = bm;                colbase = bn - 1024; stride = 1024; }
    else              { outp = Vt; rowbase = (size_t)bn - 2048; colbase = bm;        stride = 4096; }
#pragma unroll
    for (int pass = 0; pass < 8; ++pass) {
        const int r = (t >> 4) + pass * 16;
        const int c = (t & 15) * 8;
        uint4 u = *(const uint4*)&Ct[r][c];
        *(uint4*)(outp + (rowbase + r) * stride + colbase + c) = u;
    }
}

// ---------------------------------------------------------------------------
// O-projection GEMM, m97-style: A = Y [4096][1024] bf16, W = wob, C fp32.
// ---------------------------------------------------------------------------
__global__ __launch_bounds__(256) void gemm_o(const short* __restrict__ A,
                                              const short* __restrict__ W,
                                              float* __restrict__ C) {
    __shared__ __align__(16) char pool[34816];
    short (*As)[64] = (short(*)[64])pool;             // 128x64 = 16384 B
    short (*Bs)[64] = (short(*)[64])(pool + 16384);   //  64x64 =  8192 B
    const int t    = threadIdx.x;
    const int wave = t >> 6, lane = t & 63, quad = lane >> 4, l16 = lane & 15;
    const int bm = blockIdx.x * 128, bn = blockIdx.y * 64;
    const int qm = (wave >> 1) * 64, qn = (wave & 1) * 32;

    const int lrow = lane >> 3, lcol = (lane & 7) * 8;
    const short* Ag = A + (size_t)(bm + wave * 32 + lrow) * 1024 + lcol;
    const short* Wg = W + (size_t)(bn + wave * 16 + lrow) * 1024 + lcol;
    short* Al = &As[wave * 32][0];
    short* Bl = &Bs[wave * 16][0];

    floatx4 acc[4][2];
#pragma unroll
    for (int i = 0; i < 4; ++i)
#pragma unroll
        for (int j = 0; j < 2; ++j) {
            floatx4 z = {0.f, 0.f, 0.f, 0.f};
            acc[i][j] = z;
        }

    for (int k0 = 0; k0 < 1024; k0 += 64) {
        __syncthreads();
#pragma unroll
        for (int j = 0; j < 4; ++j)
            GLDS(Ag + k0 + (size_t)j * 8 * 1024, Al + j * 8 * 64);
#pragma unroll
        for (int j = 0; j < 2; ++j)
            GLDS(Wg + k0 + (size_t)j * 8 * 1024, Bl + j * 8 * 64);
        __syncthreads();
#pragma unroll
        for (int kk = 0; kk < 64; kk += 32) {
            bhalf8 af[4], bfr[2];
#pragma unroll
            for (int im = 0; im < 4; ++im)
                af[im] = *(const bhalf8*)&As[qm + im * 16 + l16][kk + quad * 8];
#pragma unroll
            for (int jn = 0; jn < 2; ++jn)
                bfr[jn] = *(const bhalf8*)&Bs[qn + jn * 16 + l16][kk + quad * 8];
#pragma unroll
            for (int im = 0; im < 4; ++im)
#pragma unroll
                for (int jn = 0; jn < 2; ++jn)
                    acc[im][jn] = __builtin_amdgcn_mfma_f32_16x16x32_bf16(
                        af[im], bfr[jn], acc[im][jn], 0, 0, 0);
        }
    }

    // ---- fp32 LDS epilogue, line-complete stores ----
    __syncthreads();
    float (*Ctf)[68] = (float(*)[68])pool;            // 128x68x4 = 34816 B
#pragma unroll
    for (int im = 0; im < 4; ++im)
#pragma unroll
        for (int jn = 0; jn < 2; ++jn)
#pragma unroll
            for (int g = 0; g < 4; ++g)
                Ctf[qm + im * 16 + quad * 4 + g][qn + jn * 16 + l16] = acc[im][jn][g];
    __syncthreads();
#pragma unroll
    for (int pass = 0; pass < 8; ++pass) {
        const int r = (t >> 4) + pass * 16;
        const int c = (t & 15) * 4;
        float4 u = *(const float4*)&Ctf[r][c];
        *(float4*)(C + (size_t)(bm + r) * 1024 + bn + c) = u;
    }
}

// ---------------------------------------------------------------------------
// Flash attention v13 — block-shared LDS K/V (8-warp flash structure, §B).
// Rounds 0-5 evidence: every scheduling variant of the per-wave-global-load
// chunk lands at ~5-6k cycles per chunk-exec per SIMD, insensitive to
// occupancy (2 vs 4 waves/SIMD) and to L2 residency (FETCH 71 vs 12.4 MB,
// same time). The invariant is the chunk structure: 16 per-wave VMEM
// instructions + Ps round-trip per chunk, duplicated in every wave.
// v13 ports the m214-proven structure: K/V staged ONCE per block into
// padded LDS, shared by 8 waves (8x fewer VMEM instr/chunk-exec; frag
// reads at LDS latency), double-buffered, ONE barrier per chunk, loads
// issued 2 chunks ahead (T14 async split).
//   grid 256 = (pair 0..7) x (bh 0..31), bid%8 = bh%8 -> head-tied XCD.
//   block: Q-tile A = 128 rows of tile (15-pair), then tile B = (pair).
//   chunks: (16-pair)*2 + (pair+1)*2 = 34 per block, uniform.
//   wave w owns rows qt*128 + w*16 .. +15 (QBLK=16).
//   LDS: Ks[2][64][72] + Vs[2][64][72] + Ps[8][16][72] = 55296 B.
//   Padded rows (72) -> 2-way-free LDS reads (reg-staging allows padding;
//   global_load_lds would not, m104/m173).
// Fixed-CB softmax (exp2(s*KS-CB), no running max) as in v7-v12.
// ---------------------------------------------------------------------------
#define MFMA_BF16 __builtin_amdgcn_mfma_f32_16x16x32_bf16

// Stage one 64-k chunk of K and V: 512 threads x 16 B each (8 KB + 8 KB).
// Thread t: row sr = t>>3 (64 rows, 8 threads/row), col sc = (t&7)*8 elems.
#define STAGE_LOAD(kregv, vregv, kk) do {                                     \
    kregv = *(const uint4*)(Kbase + (size_t)((kk) + sr) * 1024 + sc);         \
    vregv = *(const uint4*)(Vbase + (size_t)sr * 4096 + (kk) + sc);           \
    } while (0)

#define STAGE_WRITE(bufv, kregv, vregv) do {                                  \
    *(uint4*)&Ks[bufv][sr][sc] = kregv;                                       \
    *(uint4*)&Vs[bufv][sr][sc] = vregv;                                       \
    } while (0)

// One 64-k chunk for one wave (16 q-rows at qwv), K/V from LDS buf.
#define CHUNK13(bufv, k0v, qwv) do {                                          \
    bhalf8 kf_[4][2];                                                         \
    _Pragma("unroll")                                                         \
    for (int jn_ = 0; jn_ < 4; ++jn_) {                                       \
        kf_[jn_][0] = *(const bhalf8*)&Ks[bufv][jn_ * 16 + l16][quad * 8];    \
        kf_[jn_][1] = *(const bhalf8*)&Ks[bufv][jn_ * 16 + l16][32 + quad * 8]; \
    }                                                                         \
    floatx4 s_[4];                                                            \
    _Pragma("unroll")                                                         \
    for (int jn_ = 0; jn_ < 4; ++jn_) {                                       \
        floatx4 z_ = {0.f, 0.f, 0.f, 0.f};                                    \
        z_ = MFMA_BF16(qf0, kf_[jn_][0], z_, 0, 0, 0);                        \
        z_ = MFMA_BF16(qf1, kf_[jn_][1], z_, 0, 0, 0);                        \
        s_[jn_] = z_;                                                         \
    }                                                                         \
    bhalf8 vf_[4][2];          /* issued before softmax: latency hidden */    \
    _Pragma("unroll")                                                         \
    for (int nd_ = 0; nd_ < 4; ++nd_) {                                       \
        vf_[nd_][0] = *(const bhalf8*)&Vs[bufv][nd_ * 16 + l16][quad * 8];    \
        vf_[nd_][1] = *(const bhalf8*)&Vs[bufv][nd_ * 16 + l16][32 + quad * 8]; \
    }                                                                         \
    const bool partial_ = ((k0v) + 64 > (qwv));                               \
    _Pragma("unroll")                                                         \
    for (int g_ = 0; g_ < 4; ++g_) {                                          \
        const int rr_ = quad * 4 + g_;                                        \
        const int qrow_ = (qwv) + rr_;                                        \
        float e0_ = exp2f(s_[0][g_] * KS - CB);                               \
        float e1_ = exp2f(s_[1][g_] * KS - CB);                               \
        float e2_ = exp2f(s_[2][g_] * KS - CB);                               \
        float e3_ = exp2f(s_[3][g_] * KS - CB);                               \
        if (partial_) {                                                       \
            if ((k0v) + l16 > qrow_)      e0_ = 0.f;                          \
            if ((k0v) + 16 + l16 > qrow_) e1_ = 0.f;                          \
            if ((k0v) + 32 + l16 > qrow_) e2_ = 0.f;                          \
            if ((k0v) + 48 + l16 > qrow_) e3_ = 0.f;                          \
        }                                                                     \
        lsum[g_] += (e0_ + e1_) + (e2_ + e3_);                                \
        unsigned r01_ = cvt_pk_bf16(e0_, e1_);                                \
        unsigned r23_ = cvt_pk_bf16(e2_, e3_);                                \
        Ps[wave][rr_][l16]      = (short)r01_;                                \
        Ps[wave][rr_][16 + l16] = (short)(r01_ >> 16);                        \
        Ps[wave][rr_][32 + l16] = (short)r23_;                                \
        Ps[wave][rr_][48 + l16] = (short)(r23_ >> 16);                        \
    }                                                                         \
    /* same-wave LDS RAW: compiler inserts lgkmcnt drain before reads */      \
    bhalf8 ap0_ = *(const bhalf8*)&Ps[wave][l16][quad * 8];                   \
    bhalf8 ap1_ = *(const bhalf8*)&Ps[wave][l16][32 + quad * 8];              \
    _Pragma("unroll")                                                         \
    for (int nd_ = 0; nd_ < 4; ++nd_) {                                       \
        o[nd_] = MFMA_BF16(ap0_, vf_[nd_][0], o[nd_], 0, 0, 0);               \
        o[nd_] = MFMA_BF16(ap1_, vf_[nd_][1], o[nd_], 0, 0, 0);               \
    }                                                                         \
} while (0)

// Full causal sweep over one 128-row Q-tile. ncv EVEN always ((qt+1)*2):
// last chunk uses buf 1, so the next sweep's prologue write to buf 0 cannot
// collide with stragglers still reading buf 1.
#define SWEEP(qtv, ncv) do {                                                  \
    const int qw_ = (qtv) * 128 + wave * 16;                                  \
    const short* qr_ = Qbase + (size_t)(qw_ + l16) * 1024;                    \
    bhalf8 qf0 = *(const bhalf8*)(qr_ + quad * 8);                            \
    bhalf8 qf1 = *(const bhalf8*)(qr_ + 32 + quad * 8);                       \
    _Pragma("unroll")                                                         \
    for (int g_ = 0; g_ < 4; ++g_) lsum[g_] = 0.f;                            \
    _Pragma("unroll")                                                         \
    for (int nd_ = 0; nd_ < 4; ++nd_) {                                       \
        floatx4 z_ = {0.f, 0.f, 0.f, 0.f};                                    \
        o[nd_] = z_;                                                          \
    }                                                                         \
    uint4 kreg_, vreg_;                                                       \
    STAGE_LOAD(kreg_, vreg_, 0);                                              \
    STAGE_WRITE(0, kreg_, vreg_);                                             \
    if ((ncv) > 1) STAGE_LOAD(kreg_, vreg_, 64);                              \
    __syncthreads();                                                          \
    _Pragma("unroll 1")                                                       \
    for (int i_ = 0; i_ < (ncv); ++i_) {                                      \
        const int buf_ = i_ & 1;                                              \
        if (i_ + 1 < (ncv)) STAGE_WRITE(buf_ ^ 1, kreg_, vreg_);              \
        if (i_ + 2 < (ncv)) STAGE_LOAD(kreg_, vreg_, (i_ + 2) * 64);          \
        CHUNK13(buf_, i_ * 64, qw_);                                          \
        __syncthreads();                                                      \
    }                                                                         \
    _Pragma("unroll")                                                         \
    for (int g_ = 0; g_ < 4; ++g_) {                                          \
        float r_ = lsum[g_];                                                  \
        r_ += __shfl_xor(r_, 1, 64);                                          \
        r_ += __shfl_xor(r_, 2, 64);                                          \
        r_ += __shfl_xor(r_, 4, 64);                                          \
        r_ += __shfl_xor(r_, 8, 64);                                          \
        const float iv_ = 1.0f / r_;                                          \
        const int qrow_ = qw_ + quad * 4 + g_;                                \
        _Pragma("unroll")                                                     \
        for (int nd_ = 0; nd_ < 4; ++nd_)                                     \
            Y[(size_t)(b * SEQ + qrow_) * 1024 + h * 64 + nd_ * 16 + l16] =   \
                f2bf(o[nd_][g_] * iv_);                                       \
    }                                                                         \
} while (0)

__global__ __launch_bounds__(512) void attn_v13(const short* __restrict__ Qo,
                                                const short* __restrict__ Ko,
                                                const short* __restrict__ Vt,
                                                short* __restrict__ Y) {
    __shared__ __align__(16) short Ks[2][64][72];   // 18432 B, K chunk dbuf
    __shared__ __align__(16) short Vs[2][64][72];   // 18432 B, V^T chunk dbuf
    __shared__ __align__(16) short Ps[8][16][72];   // 18432 B, per-wave P

    const int t    = threadIdx.x;
    const int wave = t >> 6, lane = t & 63, quad = lane >> 4, l16 = lane & 15;
    const int bid  = (int)blockIdx.x;
    const int bh   = bid & 31, pair = bid >> 5;     // bid%8 = bh%8: XCD-tied
    const int b = bh >> 4, h = bh & 15;
    const int qtA = 15 - pair, qtB = pair;          // heavy tile first

    const short* Qbase = Qo + (size_t)b * SEQ * 1024 + h * 64;
    const short* Kbase = Ko + (size_t)b * SEQ * 1024 + h * 64;
    const short* Vbase = Vt + (size_t)h * 64 * 4096 + (size_t)b * SEQ;

    const int sr = t >> 3;            // staging row 0..63
    const int sc = (t & 7) * 8;       // staging col (elements)

    const float KS = 0.125f * 1.44269504f;   // score scale * log2(e)
    const float CB = 12.0f * 1.44269504f;    // fixed softmax offset

    float lsum[4];
    floatx4 o[4];

    SWEEP(qtA, (qtA + 1) * 2);
    SWEEP(qtB, (qtB + 1) * 2);
}

// ---------------------------------------------------------------------------
extern "C" void kernel_launch(void* const* d_in, const int* in_sizes, int n_in,
                              void* d_out, int out_size, void* d_ws, size_t ws_size,
                              hipStream_t stream) {
    const float* x  = (const float*)d_in[0];
    const float* wq = (const float*)d_in[1];
    const float* wk = (const float*)d_in[2];
    const float* wv = (const float*)d_in[3];
    const float* wo = (const float*)d_in[4];

    short* xb   = (short*)d_ws;
    short* Qo   = xb + (size_t)4096 * 1024;
    short* Ko   = Qo + (size_t)4096 * 1024;
    short* Vt   = Ko + (size_t)4096 * 1024;
    short* wall = Vt + (size_t)1024 * 4096;
    short* wob  = wall + (size_t)3 * 1024 * 1024;

    cast_x<<<dim3(2048), 256, 0, stream>>>(x, xb);
    cast_w<<<dim3(512, 4), 256, 0, stream>>>(wq, wk, wv, wo, wall);
    gemm_qkv<<<dim3(32, 24), 256, 0, stream>>>(xb, wall, Qo, Ko, Vt);
    attn_v13<<<dim3(256), 512, 0, stream>>>(Qo, Ko, Vt, xb);
    gemm_o<<<dim3(32, 16), 256, 0, stream>>>(xb, wob, (float*)d_out);
}

// Round 7
// 197.277 us; speedup vs baseline: 1.2336x; 1.0351x over previous
//
#include <hip/hip_runtime.h>

typedef short bhalf8 __attribute__((ext_vector_type(8)));   // 8 x bf16 = 4 VGPRs
typedef float floatx4 __attribute__((ext_vector_type(4)));  // MFMA C/D frag

#define D_MODEL 1024
#define SEQ     2048
#define BATCH   2
#define NHEAD   16
#define DH      64

// global -> LDS direct DMA (m97: width 16 emits global_load_lds_dwordx4).
// LDS dest is WAVE-UNIFORM base; lane i lands at base + i*16 (no padding!).
#define GLDS(g, l) __builtin_amdgcn_global_load_lds( \
    (const __attribute__((address_space(1))) void*)(g), \
    (__attribute__((address_space(3))) void*)(l), 16, 0, 0)

static __device__ __forceinline__ short f2bf(float f) {
    unsigned u = __builtin_bit_cast(unsigned, f);
    u = (u + 0x7fffu + ((u >> 16) & 1u)) >> 16;   // RNE fp32 -> bf16
    return (short)u;
}
static __device__ __forceinline__ unsigned pack2(float a, float b) {
    return (unsigned)(unsigned short)f2bf(a) | ((unsigned)(unsigned short)f2bf(b) << 16);
}
// HW packed fp32->bf16 (RNE); no builtin on gfx950, inline asm per T12 recipe.
static __device__ __forceinline__ unsigned cvt_pk_bf16(float lo, float hi) {
    unsigned r;
    asm("v_cvt_pk_bf16_f32 %0, %1, %2" : "=v"(r) : "v"(lo), "v"(hi));
    return r;
}

// ---------------------------------------------------------------------------
// Casts: fp32 -> bf16. cast_w packs wq,wk,wv,wo into one [4096][1024] region.
// ---------------------------------------------------------------------------
__global__ __launch_bounds__(256) void cast_x(const float* __restrict__ s,
                                              short* __restrict__ d) {
    int i = (blockIdx.x * 256 + threadIdx.x) * 8;
    float4 a = *(const float4*)(s + i);
    float4 b = *(const float4*)(s + i + 4);
    uint4 u = {pack2(a.x, a.y), pack2(a.z, a.w), pack2(b.x, b.y), pack2(b.z, b.w)};
    *(uint4*)(d + i) = u;
}

__global__ __launch_bounds__(256) void cast_w(const float* __restrict__ wq,
                                              const float* __restrict__ wk,
                                              const float* __restrict__ wv,
                                              const float* __restrict__ wo,
                                              short* __restrict__ dst) {
    const float* s = (blockIdx.y == 0) ? wq : (blockIdx.y == 1) ? wk
                   : (blockIdx.y == 2) ? wv : wo;
    size_t off = (size_t)blockIdx.y * (D_MODEL * D_MODEL);
    int i = (blockIdx.x * 256 + threadIdx.x) * 8;
    float4 a = *(const float4*)(s + i);
    float4 b = *(const float4*)(s + i + 4);
    uint4 u = {pack2(a.x, a.y), pack2(a.z, a.w), pack2(b.x, b.y), pack2(b.z, b.w)};
    *(uint4*)(dst + off + i) = u;
}

// ---------------------------------------------------------------------------
// Fused QKV GEMM, m97-style staging: M=4096, K=1024, N=3072.
// by<8 -> Qo[m][n], by<16 -> Ko[m][n], else Vt[n][m] (transpose via LDS).
// ---------------------------------------------------------------------------
__global__ __launch_bounds__(256) void gemm_qkv(const short* __restrict__ A,
                                                const short* __restrict__ W,
                                                short* __restrict__ Qo,
                                                short* __restrict__ Ko,
                                                short* __restrict__ Vt) {
    __shared__ __align__(16) char pool[34816];
    short (*As)[64] = (short(*)[64])pool;             // 128x64 = 16384 B
    short (*Bs)[64] = (short(*)[64])(pool + 16384);   // 128x64 = 16384 B
    const int t    = threadIdx.x;
    const int wave = t >> 6, lane = t & 63, quad = lane >> 4, l16 = lane & 15;
    const int bm = blockIdx.x * 128, by = blockIdx.y, bn = by * 128;
    const int qm = (wave >> 1) * 64, qn = (wave & 1) * 64;

    const int lrow = lane >> 3, lcol = (lane & 7) * 8;
    const short* Ag = A + (size_t)(bm + wave * 32 + lrow) * 1024 + lcol;
    const short* Wg = W + (size_t)(bn + wave * 32 + lrow) * 1024 + lcol;
    short* Al = &As[wave * 32][0];     // wave-uniform LDS bases
    short* Bl = &Bs[wave * 32][0];

    floatx4 acc[4][4];
#pragma unroll
    for (int i = 0; i < 4; ++i)
#pragma unroll
        for (int j = 0; j < 4; ++j) {
            floatx4 z = {0.f, 0.f, 0.f, 0.f};
            acc[i][j] = z;
        }

    for (int k0 = 0; k0 < 1024; k0 += 64) {
        __syncthreads();
#pragma unroll
        for (int j = 0; j < 4; ++j) {
            GLDS(Ag + k0 + (size_t)j * 8 * 1024, Al + j * 8 * 64);
            GLDS(Wg + k0 + (size_t)j * 8 * 1024, Bl + j * 8 * 64);
        }
        __syncthreads();
#pragma unroll
        for (int kk = 0; kk < 64; kk += 32) {
            bhalf8 af[4], bfr[4];
#pragma unroll
            for (int im = 0; im < 4; ++im)
                af[im] = *(const bhalf8*)&As[qm + im * 16 + l16][kk + quad * 8];
#pragma unroll
            for (int jn = 0; jn < 4; ++jn)
                bfr[jn] = *(const bhalf8*)&Bs[qn + jn * 16 + l16][kk + quad * 8];
#pragma unroll
            for (int im = 0; im < 4; ++im)
#pragma unroll
                for (int jn = 0; jn < 4; ++jn)
                    acc[im][jn] = __builtin_amdgcn_mfma_f32_16x16x32_bf16(
                        af[im], bfr[jn], acc[im][jn], 0, 0, 0);
        }
    }

    // ---- epilogue: stage C tile in LDS, line-complete wide stores ----
    __syncthreads();
    short (*Ct)[136] = (short(*)[136])pool;           // 128x136x2 = 34816 B
    const bool isV = (by >= 16);
#pragma unroll
    for (int im = 0; im < 4; ++im)
#pragma unroll
        for (int jn = 0; jn < 4; ++jn)
#pragma unroll
            for (int g = 0; g < 4; ++g) {
                const int ml = qm + im * 16 + quad * 4 + g;
                const int nl = qn + jn * 16 + l16;
                if (isV) Ct[nl][ml] = f2bf(acc[im][jn][g]);   // transposed [n][m]
                else     Ct[ml][nl] = f2bf(acc[im][jn][g]);
            }
    __syncthreads();

    short* outp;
    size_t rowbase, colbase, stride;
    if (by < 8)       { outp = Qo; rowbase = bm;                colbase = bn;        stride = 1024; }
    else if (by < 16) { outp = Ko; rowbase = bm;                colbase = bn - 1024; stride = 1024; }
    else              { outp = Vt; rowbase = (size_t)bn - 2048; colbase = bm;        stride = 4096; }
#pragma unroll
    for (int pass = 0; pass < 8; ++pass) {
        const int r = (t >> 4) + pass * 16;
        const int c = (t & 15) * 8;
        uint4 u = *(const uint4*)&Ct[r][c];
        *(uint4*)(outp + (rowbase + r) * stride + colbase + c) = u;
    }
}

// ---------------------------------------------------------------------------
// O-projection GEMM, m97-style: A = Y [4096][1024] bf16, W = wob, C fp32.
// ---------------------------------------------------------------------------
__global__ __launch_bounds__(256) void gemm_o(const short* __restrict__ A,
                                              const short* __restrict__ W,
                                              float* __restrict__ C) {
    __shared__ __align__(16) char pool[34816];
    short (*As)[64] = (short(*)[64])pool;             // 128x64 = 16384 B
    short (*Bs)[64] = (short(*)[64])(pool + 16384);   //  64x64 =  8192 B
    const int t    = threadIdx.x;
    const int wave = t >> 6, lane = t & 63, quad = lane >> 4, l16 = lane & 15;
    const int bm = blockIdx.x * 128, bn = blockIdx.y * 64;
    const int qm = (wave >> 1) * 64, qn = (wave & 1) * 32;

    const int lrow = lane >> 3, lcol = (lane & 7) * 8;
    const short* Ag = A + (size_t)(bm + wave * 32 + lrow) * 1024 + lcol;
    const short* Wg = W + (size_t)(bn + wave * 16 + lrow) * 1024 + lcol;
    short* Al = &As[wave * 32][0];
    short* Bl = &Bs[wave * 16][0];

    floatx4 acc[4][2];
#pragma unroll
    for (int i = 0; i < 4; ++i)
#pragma unroll
        for (int j = 0; j < 2; ++j) {
            floatx4 z = {0.f, 0.f, 0.f, 0.f};
            acc[i][j] = z;
        }

    for (int k0 = 0; k0 < 1024; k0 += 64) {
        __syncthreads();
#pragma unroll
        for (int j = 0; j < 4; ++j)
            GLDS(Ag + k0 + (size_t)j * 8 * 1024, Al + j * 8 * 64);
#pragma unroll
        for (int j = 0; j < 2; ++j)
            GLDS(Wg + k0 + (size_t)j * 8 * 1024, Bl + j * 8 * 64);
        __syncthreads();
#pragma unroll
        for (int kk = 0; kk < 64; kk += 32) {
            bhalf8 af[4], bfr[2];
#pragma unroll
            for (int im = 0; im < 4; ++im)
                af[im] = *(const bhalf8*)&As[qm + im * 16 + l16][kk + quad * 8];
#pragma unroll
            for (int jn = 0; jn < 2; ++jn)
                bfr[jn] = *(const bhalf8*)&Bs[qn + jn * 16 + l16][kk + quad * 8];
#pragma unroll
            for (int im = 0; im < 4; ++im)
#pragma unroll
                for (int jn = 0; jn < 2; ++jn)
                    acc[im][jn] = __builtin_amdgcn_mfma_f32_16x16x32_bf16(
                        af[im], bfr[jn], acc[im][jn], 0, 0, 0);
        }
    }

    // ---- fp32 LDS epilogue, line-complete stores ----
    __syncthreads();
    float (*Ctf)[68] = (float(*)[68])pool;            // 128x68x4 = 34816 B
#pragma unroll
    for (int im = 0; im < 4; ++im)
#pragma unroll
        for (int jn = 0; jn < 2; ++jn)
#pragma unroll
            for (int g = 0; g < 4; ++g)
                Ctf[qm + im * 16 + quad * 4 + g][qn + jn * 16 + l16] = acc[im][jn][g];
    __syncthreads();
#pragma unroll
    for (int pass = 0; pass < 8; ++pass) {
        const int r = (t >> 4) + pass * 16;
        const int c = (t & 15) * 4;
        float4 u = *(const float4*)&Ctf[r][c];
        *(float4*)(C + (size_t)(bm + r) * 1024 + bn + c) = u;
    }
}

// ---------------------------------------------------------------------------
// Flash attention v14 — v13's block-shared LDS K/V, pair split into TWO
// INDEPENDENT blocks per CU.
// v13 post-mortem: 57.9 us, occupancy 20.4% = 8 waves/CU. LDS (55296 B)
// allows 2 blocks/CU but grid=256 delivered only 1; all 8 waves of the
// single block are barrier-locked into the same chunk phase, so stall
// windows (lgkm waits, barrier drains) have nothing to overlap. VGPR=64
// leaves huge headroom. v14: grid 512, ONE Q-tile sweep per block:
//   bid <  256: heavy half, qt = 15 - (bid&255)>>5  (qt 8..15)
//   bid >= 256: light half, qt = (bid&255)>>5       (qt 0..7)
// In-order dispatch gives CU c blocks {c, 256+c} = heavy+light = 34
// chunks/CU (v13's balance) as two INDEPENDENT barrier domains that
// interleave on the SIMDs. XCD map preserved both halves (bid%8 = bh%8,
// 256%8=0) -> 2 MB K/V per XCD, L2-fit. Chunk code identical to v13.
// ---------------------------------------------------------------------------
#define MFMA_BF16 __builtin_amdgcn_mfma_f32_16x16x32_bf16

// Stage one 64-k chunk of K and V: 512 threads x 16 B each (8 KB + 8 KB).
// Thread t: row sr = t>>3 (64 rows, 8 threads/row), col sc = (t&7)*8 elems.
#define STAGE_LOAD(kregv, vregv, kk) do {                                     \
    kregv = *(const uint4*)(Kbase + (size_t)((kk) + sr) * 1024 + sc);         \
    vregv = *(const uint4*)(Vbase + (size_t)sr * 4096 + (kk) + sc);           \
    } while (0)

#define STAGE_WRITE(bufv, kregv, vregv) do {                                  \
    *(uint4*)&Ks[bufv][sr][sc] = kregv;                                       \
    *(uint4*)&Vs[bufv][sr][sc] = vregv;                                       \
    } while (0)

// One 64-k chunk for one wave (16 q-rows at qwv), K/V from LDS buf.
#define CHUNK13(bufv, k0v, qwv) do {                                          \
    bhalf8 kf_[4][2];                                                         \
    _Pragma("unroll")                                                         \
    for (int jn_ = 0; jn_ < 4; ++jn_) {                                       \
        kf_[jn_][0] = *(const bhalf8*)&Ks[bufv][jn_ * 16 + l16][quad * 8];    \
        kf_[jn_][1] = *(const bhalf8*)&Ks[bufv][jn_ * 16 + l16][32 + quad * 8]; \
    }                                                                         \
    floatx4 s_[4];                                                            \
    _Pragma("unroll")                                                         \
    for (int jn_ = 0; jn_ < 4; ++jn_) {                                       \
        floatx4 z_ = {0.f, 0.f, 0.f, 0.f};                                    \
        z_ = MFMA_BF16(qf0, kf_[jn_][0], z_, 0, 0, 0);                        \
        z_ = MFMA_BF16(qf1, kf_[jn_][1], z_, 0, 0, 0);                        \
        s_[jn_] = z_;                                                         \
    }                                                                         \
    bhalf8 vf_[4][2];          /* issued before softmax: latency hidden */    \
    _Pragma("unroll")                                                         \
    for (int nd_ = 0; nd_ < 4; ++nd_) {                                       \
        vf_[nd_][0] = *(const bhalf8*)&Vs[bufv][nd_ * 16 + l16][quad * 8];    \
        vf_[nd_][1] = *(const bhalf8*)&Vs[bufv][nd_ * 16 + l16][32 + quad * 8]; \
    }                                                                         \
    const bool partial_ = ((k0v) + 64 > (qwv));                               \
    _Pragma("unroll")                                                         \
    for (int g_ = 0; g_ < 4; ++g_) {                                          \
        const int rr_ = quad * 4 + g_;                                        \
        const int qrow_ = (qwv) + rr_;                                        \
        float e0_ = exp2f(s_[0][g_] * KS - CB);                               \
        float e1_ = exp2f(s_[1][g_] * KS - CB);                               \
        float e2_ = exp2f(s_[2][g_] * KS - CB);                               \
        float e3_ = exp2f(s_[3][g_] * KS - CB);                               \
        if (partial_) {                                                       \
            if ((k0v) + l16 > qrow_)      e0_ = 0.f;                          \
            if ((k0v) + 16 + l16 > qrow_) e1_ = 0.f;                          \
            if ((k0v) + 32 + l16 > qrow_) e2_ = 0.f;                          \
            if ((k0v) + 48 + l16 > qrow_) e3_ = 0.f;                          \
        }                                                                     \
        lsum[g_] += (e0_ + e1_) + (e2_ + e3_);                                \
        unsigned r01_ = cvt_pk_bf16(e0_, e1_);                                \
        unsigned r23_ = cvt_pk_bf16(e2_, e3_);                                \
        Ps[wave][rr_][l16]      = (short)r01_;                                \
        Ps[wave][rr_][16 + l16] = (short)(r01_ >> 16);                        \
        Ps[wave][rr_][32 + l16] = (short)r23_;                                \
        Ps[wave][rr_][48 + l16] = (short)(r23_ >> 16);                        \
    }                                                                         \
    /* same-wave LDS RAW: compiler inserts lgkmcnt drain before reads */      \
    bhalf8 ap0_ = *(const bhalf8*)&Ps[wave][l16][quad * 8];                   \
    bhalf8 ap1_ = *(const bhalf8*)&Ps[wave][l16][32 + quad * 8];              \
    _Pragma("unroll")                                                         \
    for (int nd_ = 0; nd_ < 4; ++nd_) {                                       \
        o[nd_] = MFMA_BF16(ap0_, vf_[nd_][0], o[nd_], 0, 0, 0);               \
        o[nd_] = MFMA_BF16(ap1_, vf_[nd_][1], o[nd_], 0, 0, 0);               \
    }                                                                         \
} while (0)

// Full causal sweep over one 128-row Q-tile (ncv chunks of 64 k each).
#define SWEEP(qtv, ncv) do {                                                  \
    const int qw_ = (qtv) * 128 + wave * 16;                                  \
    const short* qr_ = Qbase + (size_t)(qw_ + l16) * 1024;                    \
    bhalf8 qf0 = *(const bhalf8*)(qr_ + quad * 8);                            \
    bhalf8 qf1 = *(const bhalf8*)(qr_ + 32 + quad * 8);                       \
    _Pragma("unroll")                                                         \
    for (int g_ = 0; g_ < 4; ++g_) lsum[g_] = 0.f;                            \
    _Pragma("unroll")                                                         \
    for (int nd_ = 0; nd_ < 4; ++nd_) {                                       \
        floatx4 z_ = {0.f, 0.f, 0.f, 0.f};                                    \
        o[nd_] = z_;                                                          \
    }                                                                         \
    uint4 kreg_, vreg_;                                                       \
    STAGE_LOAD(kreg_, vreg_, 0);                                              \
    STAGE_WRITE(0, kreg_, vreg_);                                             \
    if ((ncv) > 1) STAGE_LOAD(kreg_, vreg_, 64);                              \
    __syncthreads();                                                          \
    _Pragma("unroll 1")                                                       \
    for (int i_ = 0; i_ < (ncv); ++i_) {                                      \
        const int buf_ = i_ & 1;                                              \
        if (i_ + 1 < (ncv)) STAGE_WRITE(buf_ ^ 1, kreg_, vreg_);              \
        if (i_ + 2 < (ncv)) STAGE_LOAD(kreg_, vreg_, (i_ + 2) * 64);          \
        CHUNK13(buf_, i_ * 64, qw_);                                          \
        __syncthreads();                                                      \
    }                                                                         \
    _Pragma("unroll")                                                         \
    for (int g_ = 0; g_ < 4; ++g_) {                                          \
        float r_ = lsum[g_];                                                  \
        r_ += __shfl_xor(r_, 1, 64);                                          \
        r_ += __shfl_xor(r_, 2, 64);                                          \
        r_ += __shfl_xor(r_, 4, 64);                                          \
        r_ += __shfl_xor(r_, 8, 64);                                          \
        const float iv_ = 1.0f / r_;                                          \
        const int qrow_ = qw_ + quad * 4 + g_;                                \
        _Pragma("unroll")                                                     \
        for (int nd_ = 0; nd_ < 4; ++nd_)                                     \
            Y[(size_t)(b * SEQ + qrow_) * 1024 + h * 64 + nd_ * 16 + l16] =   \
                f2bf(o[nd_][g_] * iv_);                                       \
    }                                                                         \
} while (0)

__global__ __launch_bounds__(512) void attn_v14(const short* __restrict__ Qo,
                                                const short* __restrict__ Ko,
                                                const short* __restrict__ Vt,
                                                short* __restrict__ Y) {
    __shared__ __align__(16) short Ks[2][64][72];   // 18432 B, K chunk dbuf
    __shared__ __align__(16) short Vs[2][64][72];   // 18432 B, V^T chunk dbuf
    __shared__ __align__(16) short Ps[8][16][72];   // 18432 B, per-wave P

    const int t    = threadIdx.x;
    const int wave = t >> 6, lane = t & 63, quad = lane >> 4, l16 = lane & 15;
    const int bid  = (int)blockIdx.x;
    const int bh   = bid & 31;                      // bid%8 = bh%8: XCD-tied
    const int p    = (bid & 255) >> 5;              // 0..7
    const int qt   = (bid < 256) ? (15 - p) : p;    // heavy half, then light
    const int b = bh >> 4, h = bh & 15;

    const short* Qbase = Qo + (size_t)b * SEQ * 1024 + h * 64;
    const short* Kbase = Ko + (size_t)b * SEQ * 1024 + h * 64;
    const short* Vbase = Vt + (size_t)h * 64 * 4096 + (size_t)b * SEQ;

    const int sr = t >> 3;            // staging row 0..63
    const int sc = (t & 7) * 8;       // staging col (elements)

    const float KS = 0.125f * 1.44269504f;   // score scale * log2(e)
    const float CB = 12.0f * 1.44269504f;    // fixed softmax offset

    float lsum[4];
    floatx4 o[4];

    SWEEP(qt, (qt + 1) * 2);
}

// ---------------------------------------------------------------------------
extern "C" void kernel_launch(void* const* d_in, const int* in_sizes, int n_in,
                              void* d_out, int out_size, void* d_ws, size_t ws_size,
                              hipStream_t stream) {
    const float* x  = (const float*)d_in[0];
    const float* wq = (const float*)d_in[1];
    const float* wk = (const float*)d_in[2];
    const float* wv = (const float*)d_in[3];
    const float* wo = (const float*)d_in[4];

    short* xb   = (short*)d_ws;
    short* Qo   = xb + (size_t)4096 * 1024;
    short* Ko   = Qo + (size_t)4096 * 1024;
    short* Vt   = Ko + (size_t)4096 * 1024;
    short* wall = Vt + (size_t)1024 * 4096;
    short* wob  = wall + (size_t)3 * 1024 * 1024;

    cast_x<<<dim3(2048), 256, 0, stream>>>(x, xb);
    cast_w<<<dim3(512, 4), 256, 0, stream>>>(wq, wk, wv, wo, wall);
    gemm_qkv<<<dim3(32, 24), 256, 0, stream>>>(xb, wall, Qo, Ko, Vt);
    attn_v14<<<dim3(512), 512, 0, stream>>>(Qo, Ko, Vt, xb);
    gemm_o<<<dim3(32, 16), 256, 0, stream>>>(xb, wob, (float*)d_out);
}

// Round 8
// 190.086 us; speedup vs baseline: 1.2803x; 1.0378x over previous
//
#include <hip/hip_runtime.h>

typedef short bhalf8 __attribute__((ext_vector_type(8)));   // 8 x bf16 = 4 VGPRs
typedef float floatx4 __attribute__((ext_vector_type(4)));  // MFMA C/D frag

#define D_MODEL 1024
#define SEQ     2048
#define BATCH   2
#define NHEAD   16
#define DH      64

// global -> LDS direct DMA (m97: width 16 emits global_load_lds_dwordx4).
// LDS dest is WAVE-UNIFORM base; lane i lands at base + i*16 (no padding!).
#define GLDS(g, l) __builtin_amdgcn_global_load_lds( \
    (const __attribute__((address_space(1))) void*)(g), \
    (__attribute__((address_space(3))) void*)(l), 16, 0, 0)

static __device__ __forceinline__ short f2bf(float f) {
    unsigned u = __builtin_bit_cast(unsigned, f);
    u = (u + 0x7fffu + ((u >> 16) & 1u)) >> 16;   // RNE fp32 -> bf16
    return (short)u;
}
static __device__ __forceinline__ unsigned pack2(float a, float b) {
    return (unsigned)(unsigned short)f2bf(a) | ((unsigned)(unsigned short)f2bf(b) << 16);
}
// HW packed fp32->bf16 (RNE); no builtin on gfx950, inline asm per T12 recipe.
static __device__ __forceinline__ unsigned cvt_pk_bf16(float lo, float hi) {
    unsigned r;
    asm("v_cvt_pk_bf16_f32 %0, %1, %2" : "=v"(r) : "v"(lo), "v"(hi));
    return r;
}

// ---------------------------------------------------------------------------
// Merged cast kernel: bid<2048 -> x (fp32->bf16); else wq/wk/wv/wo into wall.
// ---------------------------------------------------------------------------
__global__ __launch_bounds__(256) void cast_all(const float* __restrict__ x,
                                                const float* __restrict__ wq,
                                                const float* __restrict__ wk,
                                                const float* __restrict__ wv,
                                                const float* __restrict__ wo,
                                                short* __restrict__ xb,
                                                short* __restrict__ wall) {
    const int bid = blockIdx.x;
    const float* s;
    short* d;
    int i;
    if (bid < 2048) {
        s = x; d = xb;
        i = (bid * 256 + threadIdx.x) * 8;
    } else {
        const int wb = bid - 2048;           // 0..2047
        const int which = wb >> 9;           // 0..3
        s = (which == 0) ? wq : (which == 1) ? wk : (which == 2) ? wv : wo;
        d = wall + (size_t)which * (D_MODEL * D_MODEL);
        i = ((wb & 511) * 256 + threadIdx.x) * 8;
    }
    float4 a = *(const float4*)(s + i);
    float4 b = *(const float4*)(s + i + 4);
    uint4 u = {pack2(a.x, a.y), pack2(a.z, a.w), pack2(b.x, b.y), pack2(b.z, b.w)};
    *(uint4*)(d + i) = u;
}

// ---------------------------------------------------------------------------
// Fused QKV GEMM v2 — 256x256 tile, BK=32, RING-OF-3 counted-vmcnt pipeline.
// Old m97-style kernel: 68 us (380 TF), MfmaUtil 14%, 9.7M LDS bank
// conflicts; stall = vmcnt(0) drain at every barrier (single-buffered).
// v2 mechanisms (T4 counted vmcnt is the lever, m218 +38-73%):
//  - 3 LDS slots per operand: at K-tile kt, compute slot kt%3 while kt+1's
//    loads fly and kt+2's are issued into slot (kt+2)%3 = (kt-1)%3 (freed
//    by this iteration's barrier). ONE barrier + ONE s_waitcnt vmcnt(4)
//    per K-tile; vmcnt(0) only at the peeled last tile.
//  - BK=32 => 64-B LDS rows => frag ds_read_b128 hits all 32 banks
//    (bank = (l16*16+quad*4+w)%32) — conflict-free WITHOUT swizzle.
//    (The old 128-B rows put 16 lanes on one bank group: the 9.7M.)
//  - raw s_barrier + inline-asm vmcnt (template pattern): hipcc only
//    force-drains at __syncthreads, which the main loop never calls.
//  - T5 setprio(1) around the MFMA cluster.
// Geometry: 512 thr = 8 waves (2M x 4N), per-wave out 128x64, acc[8][4]
// (128 VGPR). Per K-tile/thread: 4 gload_lds (2 A + 2 B). LDS ring
// 3*(16K+16K) = 96 KB; epilogue Ct[128][268] (68.6 KB) aliases it.
// Grid (16,12): by<4 -> Q, by<8 -> K, else V^T (transposed in LDS).
// ---------------------------------------------------------------------------
#define MFMA_BF16 __builtin_amdgcn_mfma_f32_16x16x32_bf16

#define QISSUE(kt, s) do {                                                    \
    char* ab_ = pool + (s) * 16384 + (w * 32) * 64;                           \
    char* bb_ = pool + 49152 + (s) * 16384 + (w * 32) * 64;                   \
    GLDS(Ag + (size_t)(kt) * 32, ab_);                                        \
    GLDS(Ag + (size_t)(kt) * 32 + 16 * 1024, ab_ + 1024);                     \
    GLDS(Wg + (size_t)(kt) * 32, bb_);                                        \
    GLDS(Wg + (size_t)(kt) * 32 + 16 * 1024, bb_ + 1024);                     \
} while (0)

#define QCOMP(s) do {                                                         \
    const short(*As_)[32] = (const short(*)[32])(pool + (s) * 16384);         \
    const short(*Bs_)[32] = (const short(*)[32])(pool + 49152 + (s) * 16384); \
    bhalf8 af_[8], bf_[4];                                                    \
    _Pragma("unroll")                                                         \
    for (int m_ = 0; m_ < 8; ++m_)                                            \
        af_[m_] = *(const bhalf8*)&As_[wr * 128 + m_ * 16 + l16][quad * 8];   \
    _Pragma("unroll")                                                         \
    for (int n_ = 0; n_ < 4; ++n_)                                            \
        bf_[n_] = *(const bhalf8*)&Bs_[wc * 64 + n_ * 16 + l16][quad * 8];    \
    __builtin_amdgcn_s_setprio(1);                                            \
    _Pragma("unroll")                                                         \
    for (int m_ = 0; m_ < 8; ++m_)                                            \
        _Pragma("unroll")                                                     \
        for (int n_ = 0; n_ < 4; ++n_)                                        \
            acc[m_][n_] = MFMA_BF16(af_[m_], bf_[n_], acc[m_][n_], 0, 0, 0);  \
    __builtin_amdgcn_s_setprio(0);                                            \
} while (0)

__global__ __launch_bounds__(512) void gemm_qkv2(const short* __restrict__ A,
                                                 const short* __restrict__ W,
                                                 short* __restrict__ Qo,
                                                 short* __restrict__ Ko,
                                                 short* __restrict__ Vt) {
    __shared__ __align__(16) char pool[98304];   // ring 96 KB; epilogue aliases
    const int t    = threadIdx.x;
    const int w    = t >> 6, lane = t & 63, quad = lane >> 4, l16 = lane & 15;
    const int wr   = w >> 2, wc = w & 3;
    const int bm   = blockIdx.x * 256;
    const int by   = (int)blockIdx.y;
    const int bn   = by * 256;

    // staging pointers: thread covers A row bm+w*32+(lane>>2) (+16 for 2nd
    // load), 8 elems at col (lane&3)*8; matches GLDS lane->base+lane*16.
    const short* Ag = A + (size_t)(bm + w * 32 + (lane >> 2)) * 1024 + (lane & 3) * 8;
    const short* Wg = W + (size_t)(bn + w * 32 + (lane >> 2)) * 1024 + (lane & 3) * 8;

    floatx4 acc[8][4];
#pragma unroll
    for (int m = 0; m < 8; ++m)
#pragma unroll
        for (int n = 0; n < 4; ++n) {
            floatx4 z = {0.f, 0.f, 0.f, 0.f};
            acc[m][n] = z;
        }

    // prologue: tiles 0,1 in flight (8 per-thread loads)
    QISSUE(0, 0);
    QISSUE(1, 1);
    int sc_ = 0, sn_ = 2;
#pragma unroll 1
    for (int kt = 0; kt < 30; ++kt) {
        asm volatile("s_waitcnt vmcnt(4)" ::: "memory");  // tile kt landed
        __builtin_amdgcn_s_barrier();                     // all waves: kt valid,
                                                          // slot (kt-1)%3 free
        QISSUE(kt + 2, sn_);
        QCOMP(sc_);
        sc_ = (sc_ == 2) ? 0 : sc_ + 1;
        sn_ = (sn_ == 2) ? 0 : sn_ + 1;
    }
    asm volatile("s_waitcnt vmcnt(4)" ::: "memory");      // kt=30 (slot 0)
    __builtin_amdgcn_s_barrier();
    QCOMP(sc_);
    sc_ = (sc_ == 2) ? 0 : sc_ + 1;
    asm volatile("s_waitcnt vmcnt(0)" ::: "memory");      // kt=31 (slot 1)
    __builtin_amdgcn_s_barrier();
    QCOMP(sc_);

    // ---- epilogue: 2 halves of 128 rows staged in dead ring LDS ----
    __syncthreads();
    short (*Ct)[268] = (short(*)[268])pool;               // 128x268x2 = 68608 B
    if (by < 8) {
        short* outp = (by < 4) ? Qo : Ko;
        const int colbase = (by < 4) ? bn : bn - 1024;
        for (int hh = 0; hh < 2; ++hh) {
            if (wr == hh) {
#pragma unroll
                for (int m = 0; m < 8; ++m)
#pragma unroll
                    for (int n = 0; n < 4; ++n)
#pragma unroll
                        for (int g = 0; g < 4; ++g)
                            Ct[m * 16 + quad * 4 + g][wc * 64 + n * 16 + l16] =
                                f2bf(acc[m][n][g]);
            }
            __syncthreads();
            {
                const int r = t >> 2, c0 = (t & 3) * 64;
#pragma unroll
                for (int p = 0; p < 8; ++p)
                    *(uint4*)(outp + (size_t)(bm + hh * 128 + r) * 1024 +
                              colbase + c0 + p * 8) =
                        *(const uint4*)&Ct[r][c0 + p * 8];
            }
            __syncthreads();
        }
    } else {
        const int nbase = bn - 2048;
        for (int hh = 0; hh < 2; ++hh) {
            if ((wc >> 1) == hh) {
#pragma unroll
                for (int m = 0; m < 8; ++m)
#pragma unroll
                    for (int n = 0; n < 4; ++n)
#pragma unroll
                        for (int g = 0; g < 4; ++g)
                            Ct[wc * 64 + n * 16 + l16 - hh * 128]
                              [wr * 128 + m * 16 + quad * 4 + g] =
                                f2bf(acc[m][n][g]);
            }
            __syncthreads();
            {
                const int r = t >> 2, c0 = (t & 3) * 64;
#pragma unroll
                for (int p = 0; p < 8; ++p)
                    *(uint4*)(Vt + (size_t)(nbase + hh * 128 + r) * 4096 +
                              bm + c0 + p * 8) =
                        *(const uint4*)&Ct[r][c0 + p * 8];
            }
            __syncthreads();
        }
    }
}

// ---------------------------------------------------------------------------
// O-projection GEMM, m97-style: A = Y [4096][1024] bf16, W = wob, C fp32.
// ---------------------------------------------------------------------------
__global__ __launch_bounds__(256) void gemm_o(const short* __restrict__ A,
                                              const short* __restrict__ W,
                                              float* __restrict__ C) {
    __shared__ __align__(16) char pool[34816];
    short (*As)[64] = (short(*)[64])pool;             // 128x64 = 16384 B
    short (*Bs)[64] = (short(*)[64])(pool + 16384);   //  64x64 =  8192 B
    const int t    = threadIdx.x;
    const int wave = t >> 6, lane = t & 63, quad = lane >> 4, l16 = lane & 15;
    const int bm = blockIdx.x * 128, bn = blockIdx.y * 64;
    const int qm = (wave >> 1) * 64, qn = (wave & 1) * 32;

    const int lrow = lane >> 3, lcol = (lane & 7) * 8;
    const short* Ag = A + (size_t)(bm + wave * 32 + lrow) * 1024 + lcol;
    const short* Wg = W + (size_t)(bn + wave * 16 + lrow) * 1024 + lcol;
    short* Al = &As[wave * 32][0];
    short* Bl = &Bs[wave * 16][0];

    floatx4 acc[4][2];
#pragma unroll
    for (int i = 0; i < 4; ++i)
#pragma unroll
        for (int j = 0; j < 2; ++j) {
            floatx4 z = {0.f, 0.f, 0.f, 0.f};
            acc[i][j] = z;
        }

    for (int k0 = 0; k0 < 1024; k0 += 64) {
        __syncthreads();
#pragma unroll
        for (int j = 0; j < 4; ++j)
            GLDS(Ag + k0 + (size_t)j * 8 * 1024, Al + j * 8 * 64);
#pragma unroll
        for (int j = 0; j < 2; ++j)
            GLDS(Wg + k0 + (size_t)j * 8 * 1024, Bl + j * 8 * 64);
        __syncthreads();
#pragma unroll
        for (int kk = 0; kk < 64; kk += 32) {
            bhalf8 af[4], bfr[2];
#pragma unroll
            for (int im = 0; im < 4; ++im)
                af[im] = *(const bhalf8*)&As[qm + im * 16 + l16][kk + quad * 8];
#pragma unroll
            for (int jn = 0; jn < 2; ++jn)
                bfr[jn] = *(const bhalf8*)&Bs[qn + jn * 16 + l16][kk + quad * 8];
#pragma unroll
            for (int im = 0; im < 4; ++im)
#pragma unroll
                for (int jn = 0; jn < 2; ++jn)
                    acc[im][jn] = __builtin_amdgcn_mfma_f32_16x16x32_bf16(
                        af[im], bfr[jn], acc[im][jn], 0, 0, 0);
        }
    }

    // ---- fp32 LDS epilogue, line-complete stores ----
    __syncthreads();
    float (*Ctf)[68] = (float(*)[68])pool;            // 128x68x4 = 34816 B
#pragma unroll
    for (int im = 0; im < 4; ++im)
#pragma unroll
        for (int jn = 0; jn < 2; ++jn)
#pragma unroll
            for (int g = 0; g < 4; ++g)
                Ctf[qm + im * 16 + quad * 4 + g][qn + jn * 16 + l16] = acc[im][jn][g];
    __syncthreads();
#pragma unroll
    for (int pass = 0; pass < 8; ++pass) {
        const int r = (t >> 4) + pass * 16;
        const int c = (t & 15) * 4;
        float4 u = *(const float4*)&Ctf[r][c];
        *(float4*)(C + (size_t)(bm + r) * 1024 + bn + c) = u;
    }
}

// ---------------------------------------------------------------------------
// Flash attention v14 — block-shared LDS K/V, 2 independent blocks per CU.
// (unchanged from round 7: 512 blocks, heavy half bid<256 / light half.)
// ---------------------------------------------------------------------------

// Stage one 64-k chunk of K and V: 512 threads x 16 B each (8 KB + 8 KB).
#define STAGE_LOAD(kregv, vregv, kk) do {                                     \
    kregv = *(const uint4*)(Kbase + (size_t)((kk) + sr) * 1024 + sc);         \
    vregv = *(const uint4*)(Vbase + (size_t)sr * 4096 + (kk) + sc);           \
    } while (0)

#define STAGE_WRITE(bufv, kregv, vregv) do {                                  \
    *(uint4*)&Ks[bufv][sr][sc] = kregv;                                       \
    *(uint4*)&Vs[bufv][sr][sc] = vregv;                                       \
    } while (0)

// One 64-k chunk for one wave (16 q-rows at qwv), K/V from LDS buf.
#define CHUNK13(bufv, k0v, qwv) do {                                          \
    bhalf8 kf_[4][2];                                                         \
    _Pragma("unroll")                                                         \
    for (int jn_ = 0; jn_ < 4; ++jn_) {                                       \
        kf_[jn_][0] = *(const bhalf8*)&Ks[bufv][jn_ * 16 + l16][quad * 8];    \
        kf_[jn_][1] = *(const bhalf8*)&Ks[bufv][jn_ * 16 + l16][32 + quad * 8]; \
    }                                                                         \
    floatx4 s_[4];                                                            \
    _Pragma("unroll")                                                         \
    for (int jn_ = 0; jn_ < 4; ++jn_) {                                       \
        floatx4 z_ = {0.f, 0.f, 0.f, 0.f};                                    \
        z_ = MFMA_BF16(qf0, kf_[jn_][0], z_, 0, 0, 0);                        \
        z_ = MFMA_BF16(qf1, kf_[jn_][1], z_, 0, 0, 0);                        \
        s_[jn_] = z_;                                                         \
    }                                                                         \
    bhalf8 vf_[4][2];          /* issued before softmax: latency hidden */    \
    _Pragma("unroll")                                                         \
    for (int nd_ = 0; nd_ < 4; ++nd_) {                                       \
        vf_[nd_][0] = *(const bhalf8*)&Vs[bufv][nd_ * 16 + l16][quad * 8];    \
        vf_[nd_][1] = *(const bhalf8*)&Vs[bufv][nd_ * 16 + l16][32 + quad * 8]; \
    }                                                                         \
    const bool partial_ = ((k0v) + 64 > (qwv));                               \
    _Pragma("unroll")                                                         \
    for (int g_ = 0; g_ < 4; ++g_) {                                          \
        const int rr_ = quad * 4 + g_;                                        \
        const int qrow_ = (qwv) + rr_;                                        \
        float e0_ = exp2f(s_[0][g_] * KS - CB);                               \
        float e1_ = exp2f(s_[1][g_] * KS - CB);                               \
        float e2_ = exp2f(s_[2][g_] * KS - CB);                               \
        float e3_ = exp2f(s_[3][g_] * KS - CB);                               \
        if (partial_) {                                                       \
            if ((k0v) + l16 > qrow_)      e0_ = 0.f;                          \
            if ((k0v) + 16 + l16 > qrow_) e1_ = 0.f;                          \
            if ((k0v) + 32 + l16 > qrow_) e2_ = 0.f;                          \
            if ((k0v) + 48 + l16 > qrow_) e3_ = 0.f;                          \
        }                                                                     \
        lsum[g_] += (e0_ + e1_) + (e2_ + e3_);                                \
        unsigned r01_ = cvt_pk_bf16(e0_, e1_);                                \
        unsigned r23_ = cvt_pk_bf16(e2_, e3_);                                \
        Ps[wave][rr_][l16]      = (short)r01_;                                \
        Ps[wave][rr_][16 + l16] = (short)(r01_ >> 16);                        \
        Ps[wave][rr_][32 + l16] = (short)r23_;                                \
        Ps[wave][rr_][48 + l16] = (short)(r23_ >> 16);                        \
    }                                                                         \
    /* same-wave LDS RAW: compiler inserts lgkmcnt drain before reads */      \
    bhalf8 ap0_ = *(const bhalf8*)&Ps[wave][l16][quad * 8];                   \
    bhalf8 ap1_ = *(const bhalf8*)&Ps[wave][l16][32 + quad * 8];              \
    _Pragma("unroll")                                                         \
    for (int nd_ = 0; nd_ < 4; ++nd_) {                                       \
        o[nd_] = MFMA_BF16(ap0_, vf_[nd_][0], o[nd_], 0, 0, 0);               \
        o[nd_] = MFMA_BF16(ap1_, vf_[nd_][1], o[nd_], 0, 0, 0);               \
    }                                                                         \
} while (0)

// Full causal sweep over one 128-row Q-tile (ncv chunks of 64 k each).
#define SWEEP(qtv, ncv) do {                                                  \
    const int qw_ = (qtv) * 128 + wave * 16;                                  \
    const short* qr_ = Qbase + (size_t)(qw_ + l16) * 1024;                    \
    bhalf8 qf0 = *(const bhalf8*)(qr_ + quad * 8);                            \
    bhalf8 qf1 = *(const bhalf8*)(qr_ + 32 + quad * 8);                       \
    _Pragma("unroll")                                                         \
    for (int g_ = 0; g_ < 4; ++g_) lsum[g_] = 0.f;                            \
    _Pragma("unroll")                                                         \
    for (int nd_ = 0; nd_ < 4; ++nd_) {                                       \
        floatx4 z_ = {0.f, 0.f, 0.f, 0.f};                                    \
        o[nd_] = z_;                                                          \
    }                                                                         \
    uint4 kreg_, vreg_;                                                       \
    STAGE_LOAD(kreg_, vreg_, 0);                                              \
    STAGE_WRITE(0, kreg_, vreg_);                                             \
    if ((ncv) > 1) STAGE_LOAD(kreg_, vreg_, 64);                              \
    __syncthreads();                                                          \
    _Pragma("unroll 1")                                                       \
    for (int i_ = 0; i_ < (ncv); ++i_) {                                      \
        const int buf_ = i_ & 1;                                              \
        if (i_ + 1 < (ncv)) STAGE_WRITE(buf_ ^ 1, kreg_, vreg_);              \
        if (i_ + 2 < (ncv)) STAGE_LOAD(kreg_, vreg_, (i_ + 2) * 64);          \
        CHUNK13(buf_, i_ * 64, qw_);                                          \
        __syncthreads();                                                      \
    }                                                                         \
    _Pragma("unroll")                                                         \
    for (int g_ = 0; g_ < 4; ++g_) {                                          \
        float r_ = lsum[g_];                                                  \
        r_ += __shfl_xor(r_, 1, 64);                                          \
        r_ += __shfl_xor(r_, 2, 64);                                          \
        r_ += __shfl_xor(r_, 4, 64);                                          \
        r_ += __shfl_xor(r_, 8, 64);                                          \
        const float iv_ = 1.0f / r_;                                          \
        const int qrow_ = qw_ + quad * 4 + g_;                                \
        _Pragma("unroll")                                                     \
        for (int nd_ = 0; nd_ < 4; ++nd_)                                     \
            Y[(size_t)(b * SEQ + qrow_) * 1024 + h * 64 + nd_ * 16 + l16] =   \
                f2bf(o[nd_][g_] * iv_);                                       \
    }                                                                         \
} while (0)

__global__ __launch_bounds__(512) void attn_v14(const short* __restrict__ Qo,
                                                const short* __restrict__ Ko,
                                                const short* __restrict__ Vt,
                                                short* __restrict__ Y) {
    __shared__ __align__(16) short Ks[2][64][72];   // 18432 B, K chunk dbuf
    __shared__ __align__(16) short Vs[2][64][72];   // 18432 B, V^T chunk dbuf
    __shared__ __align__(16) short Ps[8][16][72];   // 18432 B, per-wave P

    const int t    = threadIdx.x;
    const int wave = t >> 6, lane = t & 63, quad = lane >> 4, l16 = lane & 15;
    const int bid  = (int)blockIdx.x;
    const int bh   = bid & 31;                      // bid%8 = bh%8: XCD-tied
    const int p    = (bid & 255) >> 5;              // 0..7
    const int qt   = (bid < 256) ? (15 - p) : p;    // heavy half, then light
    const int b = bh >> 4, h = bh & 15;

    const short* Qbase = Qo + (size_t)b * SEQ * 1024 + h * 64;
    const short* Kbase = Ko + (size_t)b * SEQ * 1024 + h * 64;
    const short* Vbase = Vt + (size_t)h * 64 * 4096 + (size_t)b * SEQ;

    const int sr = t >> 3;            // staging row 0..63
    const int sc = (t & 7) * 8;       // staging col (elements)

    const float KS = 0.125f * 1.44269504f;   // score scale * log2(e)
    const float CB = 12.0f * 1.44269504f;    // fixed softmax offset

    float lsum[4];
    floatx4 o[4];

    SWEEP(qt, (qt + 1) * 2);
}

// ---------------------------------------------------------------------------
extern "C" void kernel_launch(void* const* d_in, const int* in_sizes, int n_in,
                              void* d_out, int out_size, void* d_ws, size_t ws_size,
                              hipStream_t stream) {
    const float* x  = (const float*)d_in[0];
    const float* wq = (const float*)d_in[1];
    const float* wk = (const float*)d_in[2];
    const float* wv = (const float*)d_in[3];
    const float* wo = (const float*)d_in[4];

    short* xb   = (short*)d_ws;
    short* Qo   = xb + (size_t)4096 * 1024;
    short* Ko   = Qo + (size_t)4096 * 1024;
    short* Vt   = Ko + (size_t)4096 * 1024;
    short* wall = Vt + (size_t)1024 * 4096;
    short* wob  = wall + (size_t)3 * 1024 * 1024;

    cast_all<<<dim3(4096), 256, 0, stream>>>(x, wq, wk, wv, wo, xb, wall);
    gemm_qkv2<<<dim3(16, 12), 512, 0, stream>>>(xb, wall, Qo, Ko, Vt);
    attn_v14<<<dim3(512), 512, 0, stream>>>(Qo, Ko, Vt, xb);
    gemm_o<<<dim3(32, 16), 256, 0, stream>>>(xb, wob, (float*)d_out);
}